// Round 14
// baseline (400.285 us; speedup 1.0000x reference)
//
#include <hip/hip_runtime.h>
#include <hip/hip_bf16.h>

#define NN 50000
#define EE 600000
#define RR 8
#define NSEG (NN*RR)                     // 400000
#define NB_SCAN ((NSEG + 1023)/1024)     // 391

typedef unsigned int u32;
typedef __attribute__((ext_vector_type(8))) short bf16x8;
typedef __attribute__((ext_vector_type(4))) float f32x4;
typedef __attribute__((ext_vector_type(4))) u32 u32x4;

// fp32 -> bf16 round-to-nearest-even (finite inputs only)
__device__ inline unsigned short f2bf(float f){
  u32 u = __float_as_uint(f);
  u32 r = (u + 0x7fffu + ((u >> 16) & 1u)) >> 16;
  return (unsigned short)r;
}
__device__ inline float bf2f(unsigned short b){ return __uint_as_float((u32)b << 16); }

#define GLD16(g, l)  __builtin_amdgcn_global_load_lds( \
    (const __attribute__((address_space(1))) void*)(g), \
    (__attribute__((address_space(3))) void*)(l), 16, 0, 0)

// ---------------- conversion: fp32 -> bf16, 4 elems/thread ----------------
__global__ void cvt_k(const float* __restrict__ in, unsigned short* __restrict__ out, int n4){
  int i = blockIdx.x * 256 + threadIdx.x;
  if (i >= n4) return;
  float4 v = ((const float4*)in)[i];
  ushort4 o;
  o.x = f2bf(v.x); o.y = f2bf(v.y); o.z = f2bf(v.z); o.w = f2bf(v.w);
  ((ushort4*)out)[i] = o;
}

// ---------------- pack B (W stack) into MFMA fragment order ----------------
// frag id = k32*8 + nf; within frag: lane*8 + i
// element: B[k32*32 + (lane>>4)*8 + i][nf*16 + (lane&15)]
__global__ void pack_k(const float* __restrict__ Wrel, const float* __restrict__ root,
                       short* __restrict__ Bp, int nk32, int krel){
  int tid = blockIdx.x * 256 + threadIdx.x;
  if (tid >= nk32 * 512) return;
  int lane = tid & 63;
  int nf   = (tid >> 6) & 7;
  int k32  = tid >> 9;
  int col  = nf * 16 + (lane & 15);
  short vals[8];
#pragma unroll
  for (int i = 0; i < 8; ++i){
    int kk = k32 * 32 + ((lane >> 4) << 3) + i;
    float f = (kk < krel) ? Wrel[(size_t)kk * 128 + col]
                          : root[(size_t)(kk - krel) * 128 + col];
    vals[i] = (short)f2bf(f);
  }
  *(bf16x8*)(Bp + (size_t)tid * 8) = *(const bf16x8*)vals;
}

// ---------------- CSR build (dst-major: seg = dst*8 + r) -------------------
__global__ void count_k(const int* __restrict__ dst, const int* __restrict__ et,
                        u32* __restrict__ cnt){
  int e = blockIdx.x * 256 + threadIdx.x;
  if (e >= EE) return;
  atomicAdd(&cnt[(size_t)dst[e] * RR + et[e]], 1u);
}

__global__ void scan1_k(const u32* __restrict__ cnt, u32* __restrict__ offs, u32* __restrict__ bsum){
  __shared__ u32 s[512];
  int t = threadIdx.x;                       // 256 threads
  int base = blockIdx.x * 1024 + t * 4;
  u32 loc[4]; u32 sum = 0;
#pragma unroll
  for (int i = 0; i < 4; ++i){ loc[i] = (base + i < NSEG) ? cnt[base + i] : 0u; sum += loc[i]; }
  int pb = 0;
  s[t] = sum; __syncthreads();
  for (int off = 1; off < 256; off <<= 1){
    u32 v = s[pb * 256 + t];
    if (t >= off) v += s[pb * 256 + t - off];
    s[(pb ^ 1) * 256 + t] = v; pb ^= 1; __syncthreads();
  }
  u32 incl = s[pb * 256 + t];
  u32 excl = incl - sum;
  if (t == 255) bsum[blockIdx.x] = incl;
  u32 run = excl;
#pragma unroll
  for (int i = 0; i < 4; ++i){ if (base + i < NSEG) offs[base + i] = run; run += loc[i]; }
}

__global__ void scan2_k(u32* __restrict__ bsum){
  __shared__ u32 s[1024];
  int t = threadIdx.x;                       // 512 threads
  u32 v = (t < NB_SCAN) ? bsum[t] : 0u;
  int pb = 0;
  s[t] = v; __syncthreads();
  for (int off = 1; off < 512; off <<= 1){
    u32 x = s[pb * 512 + t];
    if (t >= off) x += s[pb * 512 + t - off];
    s[(pb ^ 1) * 512 + t] = x; pb ^= 1; __syncthreads();
  }
  u32 incl = s[pb * 512 + t];
  if (t < NB_SCAN) bsum[t] = incl - v;       // exclusive
}

__global__ void scan3_k(u32* __restrict__ offs, const u32* __restrict__ bsum){
  int t = threadIdx.x;
  int base = blockIdx.x * 1024 + t * 4;
  u32 add = bsum[blockIdx.x];
#pragma unroll
  for (int i = 0; i < 4; ++i){ if (base + i < NSEG) offs[base + i] += add; }
  if (blockIdx.x == 0 && t == 0) offs[NSEG] = EE;
}

// fill: edge record src | (r<<16); reuse cnt as cursor (atomicSub)
__global__ void fill_k(const int* __restrict__ src, const int* __restrict__ dst,
                       const int* __restrict__ et, const u32* __restrict__ offs,
                       u32* __restrict__ cnt, u32* __restrict__ elist){
  int e = blockIdx.x * 256 + threadIdx.x;
  if (e >= EE) return;
  int r = et[e];
  int s = dst[e] * RR + r;
  u32 p = atomicSub(&cnt[s], 1u);
  elist[offs[s] + p - 1] = (u32)src[e] | ((u32)r << 16);
}

// ---------------- res projection: resb = bf16(x @ res_w + res_b) ----------
__launch_bounds__(256, 4)
__global__ void resg_k(const unsigned short* __restrict__ xb, const short* __restrict__ Bp,
                       const float* __restrict__ rb, unsigned short* __restrict__ resb){
  const int tid = threadIdx.x;
  const int w = tid >> 6, l = tid & 63;
  const int sub = l >> 4, llr = l & 15;
  const int rowbase = blockIdx.x * 64 + w * 16;
  int vr = rowbase + llr; if (vr > NN - 1) vr = NN - 1;
  f32x4 acc[8] = {};
#pragma unroll
  for (int t = 0; t < 4; ++t){
    bf16x8 af = *(const bf16x8*)(xb + (size_t)vr * 128 + (t * 4 + sub) * 8);
    const short* bb = Bp + (size_t)(t * 8) * 512 + l * 8;
#pragma unroll
    for (int nf = 0; nf < 8; ++nf){
      bf16x8 bq = *(const bf16x8*)(bb + nf * 512);
      acc[nf] = __builtin_amdgcn_mfma_f32_16x16x32_bf16(af, bq, acc[nf], 0, 0, 0);
    }
  }
  const int lr = l >> 4, lc = l & 15;
#pragma unroll
  for (int nf = 0; nf < 8; ++nf){
    int col = nf * 16 + lc;
    float bv = rb[col];
#pragma unroll
    for (int r = 0; r < 4; ++r){
      int row = rowbase + lr * 4 + r;
      if (row < NN) resb[(size_t)row * 128 + col] = f2bf(acc[nf][r] + bv);
    }
  }
}

// -------- transform: yw[s][m][0..128) = h[m] @ Bslice_s -------------------
// grid = 782 mtiles x 9 slices (consecutive blocks share mtile -> L2 A reuse)
// Single A-stage (16 KB), ONE barrier, 32 MFMA/wave, B direct from L2,
// LDS-transpose epilogue for coalesced 16B stores of the 115 MB yw.
__launch_bounds__(256, 6)
__global__ void trans_k(const unsigned short* __restrict__ h, const short* __restrict__ Bp,
                        unsigned short* __restrict__ yw){
  __shared__ short alds[8192];               // phase1: [chunk16][row64][8]; phase2: [row64][col128]
  const int tid = threadIdx.x;
  const int w = tid >> 6, l = tid & 63;
  const int mt = blockIdx.x / 9, s = blockIdx.x % 9;
  const int wm = w >> 1, wn = w & 1;
  const int sub = l >> 4, llr = l & 15;
  const int mbase = mt * 64;
  int arow = mbase + l; if (arow > NN - 1) arow = NN - 1;

#pragma unroll
  for (int i = 0; i < 4; ++i)
    GLD16(h + (size_t)arow * 128 + (i * 4 + w) * 8, alds + (size_t)((i * 4 + w) * 64 + l) * 8);
  __syncthreads();

  f32x4 acc[2][4] = {};
#pragma unroll
  for (int q = 0; q < 4; ++q){
    bf16x8 af0 = *(const bf16x8*)(alds + (size_t)((q * 4 + sub) * 64 + wm * 32 + llr) * 8);
    bf16x8 af1 = *(const bf16x8*)(alds + (size_t)((q * 4 + sub) * 64 + wm * 32 + 16 + llr) * 8);
    const short* bb = Bp + ((size_t)((s * 4 + q) * 8 + wn * 4)) * 512 + l * 8;
#pragma unroll
    for (int nf = 0; nf < 4; ++nf){
      bf16x8 bq = *(const bf16x8*)(bb + nf * 512);
      acc[0][nf] = __builtin_amdgcn_mfma_f32_16x16x32_bf16(af0, bq, acc[0][nf], 0, 0, 0);
      acc[1][nf] = __builtin_amdgcn_mfma_f32_16x16x32_bf16(af1, bq, acc[1][nf], 0, 0, 0);
    }
  }
  __syncthreads();                           // all A-frag reads done before reuse

  const int lr = l >> 4, lc = l & 15;
#pragma unroll
  for (int mf = 0; mf < 2; ++mf)
#pragma unroll
    for (int nf = 0; nf < 4; ++nf)
#pragma unroll
      for (int r = 0; r < 4; ++r)
        alds[(wm * 32 + mf * 16 + lr * 4 + r) * 128 + wn * 64 + nf * 16 + lc] =
            (short)f2bf(acc[mf][nf][r]);
  __syncthreads();

  unsigned short* dst = yw + (size_t)s * NN * 128;
#pragma unroll
  for (int i = 0; i < 4; ++i){
    int c = i * 256 + tid, row = c >> 4, p = c & 15;   // [64 rows][16 chunks of 8]
    if (mbase + row < NN)
      *(u32x4*)(dst + (size_t)(mbase + row) * 128 + p * 8) =
          *(const u32x4*)(alds + (size_t)(row * 128 + p * 8));
  }
}

// -------- fused aggregate+epilogue: out[v] = res + relu(conv + bias) -------
// 8-lane group per dst row v; its 8 segments are CONTIGUOUS (dst-major CSR):
// walk offs[8v]..offs[8v+8] edges, scale each gathered yw-row by 1/deg(r_e)
// (cndmask-tree select, no shfl inside the divergent loop), add root slice.
template<int OUTMODE>
__launch_bounds__(256, 8)
__global__ void aggf_k(const u32* __restrict__ offs, const u32* __restrict__ elist,
                       const unsigned short* __restrict__ yw,
                       const float* __restrict__ bias,
                       const unsigned short* __restrict__ resb,
                       float* __restrict__ outf, unsigned short* __restrict__ outb){
  const int tid = threadIdx.x;
  const int g = tid >> 3, ll8 = tid & 7;
  int v = blockIdx.x * 32 + g; if (v > NN - 1) v = NN - 1;
  const int lane0 = g * 8;

  u32 ob = offs[v * 8 + ll8], oe = offs[v * 8 + ll8 + 1];
  float inv_own = (oe > ob) ? 1.f / (float)(oe - ob) : 0.f;
  // broadcast the 8 inverse degrees (all lanes active here)
  float i0 = __shfl(inv_own, lane0 + 0), i1 = __shfl(inv_own, lane0 + 1);
  float i2 = __shfl(inv_own, lane0 + 2), i3 = __shfl(inv_own, lane0 + 3);
  float i4 = __shfl(inv_own, lane0 + 4), i5 = __shfl(inv_own, lane0 + 5);
  float i6 = __shfl(inv_own, lane0 + 6), i7 = __shfl(inv_own, lane0 + 7);
  u32 beg = __shfl(ob, lane0);
  u32 endall = __shfl(oe, lane0 + 7);

  float acc[16];
#pragma unroll
  for (int i = 0; i < 16; ++i) acc[i] = 0.f;

  const unsigned short* ybase = yw + (size_t)ll8 * 16;
  const size_t plane = (size_t)NN * 128;

#define SEL(r, out_) do{ u32 r_ = (r); \
    float a_ = (r_ & 1) ? i1 : i0, b_ = (r_ & 1) ? i3 : i2; \
    float c_ = (r_ & 1) ? i5 : i4, d_ = (r_ & 1) ? i7 : i6; \
    float ab_ = (r_ & 2) ? b_ : a_, cd_ = (r_ & 2) ? d_ : c_; \
    out_ = (r_ & 4) ? cd_ : ab_; }while(0)

  u32 e = beg;
  for (; e + 2 <= endall; e += 2){
    u32 r0 = elist[e], r1 = elist[e + 1];
    const unsigned short* p0 = ybase + (size_t)(r0 >> 16) * plane + (size_t)(r0 & 0xffffu) * 128;
    const unsigned short* p1 = ybase + (size_t)(r1 >> 16) * plane + (size_t)(r1 & 0xffffu) * 128;
    u32x4 a0 = *(const u32x4*)p0, a1 = *(const u32x4*)(p0 + 8);
    u32x4 b0 = *(const u32x4*)p1, b1 = *(const u32x4*)(p1 + 8);
    float s0, s1; SEL(r0 >> 16, s0); SEL(r1 >> 16, s1);
#pragma unroll
    for (int i = 0; i < 4; ++i){
      acc[2*i]     += __uint_as_float(a0[i] << 16)         * s0 + __uint_as_float(b0[i] << 16)         * s1;
      acc[2*i+1]   += __uint_as_float(a0[i] & 0xffff0000u) * s0 + __uint_as_float(b0[i] & 0xffff0000u) * s1;
      acc[8+2*i]   += __uint_as_float(a1[i] << 16)         * s0 + __uint_as_float(b1[i] << 16)         * s1;
      acc[8+2*i+1] += __uint_as_float(a1[i] & 0xffff0000u) * s0 + __uint_as_float(b1[i] & 0xffff0000u) * s1;
    }
  }
  if (e < endall){
    u32 r0 = elist[e];
    const unsigned short* p0 = ybase + (size_t)(r0 >> 16) * plane + (size_t)(r0 & 0xffffu) * 128;
    u32x4 a0 = *(const u32x4*)p0, a1 = *(const u32x4*)(p0 + 8);
    float s0; SEL(r0 >> 16, s0);
#pragma unroll
    for (int i = 0; i < 4; ++i){
      acc[2*i]     += __uint_as_float(a0[i] << 16)         * s0;
      acc[2*i+1]   += __uint_as_float(a0[i] & 0xffff0000u) * s0;
      acc[8+2*i]   += __uint_as_float(a1[i] << 16)         * s0;
      acc[8+2*i+1] += __uint_as_float(a1[i] & 0xffff0000u) * s0;
    }
  }
#undef SEL

  // + root slice (plane 8), + bias, relu, + res
  const unsigned short* rp = ybase + (size_t)8 * plane + (size_t)v * 128;
  u32x4 q0 = *(const u32x4*)rp, q1 = *(const u32x4*)(rp + 8);
  const float* bp = bias + ll8 * 16;
  f32x4 bv0 = *(const f32x4*)bp, bv1 = *(const f32x4*)(bp + 4);
  f32x4 bv2 = *(const f32x4*)(bp + 8), bv3 = *(const f32x4*)(bp + 12);
  float bvs[16] = {bv0[0],bv0[1],bv0[2],bv0[3], bv1[0],bv1[1],bv1[2],bv1[3],
                   bv2[0],bv2[1],bv2[2],bv2[3], bv3[0],bv3[1],bv3[2],bv3[3]};
  const unsigned short* rr = resb + (size_t)v * 128 + ll8 * 16;
  u32x4 e0 = *(const u32x4*)rr, e1 = *(const u32x4*)(rr + 8);
  float outv[16];
#pragma unroll
  for (int i = 0; i < 4; ++i){
    outv[2*i]     = acc[2*i]     + __uint_as_float(q0[i] << 16)         + bvs[2*i];
    outv[2*i+1]   = acc[2*i+1]   + __uint_as_float(q0[i] & 0xffff0000u) + bvs[2*i+1];
    outv[8+2*i]   = acc[8+2*i]   + __uint_as_float(q1[i] << 16)         + bvs[8+2*i];
    outv[8+2*i+1] = acc[8+2*i+1] + __uint_as_float(q1[i] & 0xffff0000u) + bvs[8+2*i+1];
  }
  float resv[16];
#pragma unroll
  for (int i = 0; i < 4; ++i){
    resv[2*i]     = __uint_as_float(e0[i] << 16);
    resv[2*i+1]   = __uint_as_float(e0[i] & 0xffff0000u);
    resv[8+2*i]   = __uint_as_float(e1[i] << 16);
    resv[8+2*i+1] = __uint_as_float(e1[i] & 0xffff0000u);
  }
#pragma unroll
  for (int i = 0; i < 16; ++i) outv[i] = resv[i] + fmaxf(outv[i], 0.f);

  if (OUTMODE == 1){
    u32x4 o0, o1;
#pragma unroll
    for (int i = 0; i < 4; ++i){
      o0[i] = (u32)f2bf(outv[2*i])   | ((u32)f2bf(outv[2*i+1])   << 16);
      o1[i] = (u32)f2bf(outv[8+2*i]) | ((u32)f2bf(outv[8+2*i+1]) << 16);
    }
    unsigned short* op = outb + (size_t)v * 128 + ll8 * 16;
    *(u32x4*)op = o0; *(u32x4*)(op + 8) = o1;
  } else {
    float* op = outf + (size_t)v * 128 + ll8 * 16;
#pragma unroll
    for (int i = 0; i < 4; ++i){
      f32x4 t; t[0] = outv[i*4]; t[1] = outv[i*4+1]; t[2] = outv[i*4+2]; t[3] = outv[i*4+3];
      *(f32x4*)(op + i * 4) = t;
    }
  }
}

extern "C" void kernel_launch(void* const* d_in, const int* in_sizes, int n_in,
                              void* d_out, int out_size, void* d_ws, size_t ws_size,
                              hipStream_t stream){
  const float* x  = (const float*)d_in[0];
  const int*   ei = (const int*)d_in[1];
  const int*   et = (const int*)d_in[2];
  const float* W1 = (const float*)d_in[3];
  const float* r1 = (const float*)d_in[4];
  const float* b1 = (const float*)d_in[5];
  const float* W2 = (const float*)d_in[6];
  const float* r2 = (const float*)d_in[7];
  const float* b2 = (const float*)d_in[8];
  const float* W3 = (const float*)d_in[9];
  const float* r3 = (const float*)d_in[10];
  const float* b3 = (const float*)d_in[11];
  const float* rw = (const float*)d_in[12];
  const float* rb = (const float*)d_in[13];
  const int* srcv = ei;
  const int* dstv = ei + EE;

  char* p = (char*)d_ws;
  auto take = [&](size_t b)->char*{ char* q = p; p += (b + 255) & ~(size_t)255; return q; };
  unsigned short* yw   = (unsigned short*)take((size_t)9 * NN * 128 * 2);  // 115.2 MB
  unsigned short* xb   = (unsigned short*)take((size_t)NN * 128 * 2);
  unsigned short* h1   = (unsigned short*)take((size_t)NN * 128 * 2);
  unsigned short* h2   = (unsigned short*)take((size_t)NN * 128 * 2);
  unsigned short* resb = (unsigned short*)take((size_t)NN * 128 * 2);
  short* Bp1 = (short*)take(36 * 4096 * 2);
  short* Bp2 = (short*)take(36 * 4096 * 2);
  short* Bp3 = (short*)take(36 * 4096 * 2);
  short* BpR = (short*)take(4 * 4096 * 2);
  u32* cnt   = (u32*)take((size_t)NSEG * 4);
  u32* offs  = (u32*)take((size_t)(NSEG + 1) * 4);
  u32* elist = (u32*)take((size_t)EE * 4);
  u32* bsum  = (u32*)take((size_t)NB_SCAN * 4);

  hipMemsetAsync(cnt, 0, (size_t)NSEG * 4, stream);

  // conversions + weight packing (once)
  cvt_k<<<(NN * 128 / 4 + 255) / 256, 256, 0, stream>>>(x, xb, NN * 128 / 4);
  pack_k<<<(36 * 512 + 255) / 256, 256, 0, stream>>>(W1, r1, Bp1, 36, 1024);
  pack_k<<<(36 * 512 + 255) / 256, 256, 0, stream>>>(W2, r2, Bp2, 36, 1024);
  pack_k<<<(36 * 512 + 255) / 256, 256, 0, stream>>>(W3, r3, Bp3, 36, 1024);
  pack_k<<<(4 * 512 + 255) / 256, 256, 0, stream>>>(nullptr, rw, BpR, 4, 0);

  // CSR over segments (dst*8 + r), once for all layers
  count_k<<<(EE + 255) / 256, 256, 0, stream>>>(dstv, et, cnt);
  scan1_k<<<NB_SCAN, 256, 0, stream>>>(cnt, offs, bsum);
  scan2_k<<<1, 512, 0, stream>>>(bsum);
  scan3_k<<<NB_SCAN, 256, 0, stream>>>(offs, bsum);
  fill_k<<<(EE + 255) / 256, 256, 0, stream>>>(srcv, dstv, et, offs, cnt, elist);

  const int GT = 782 * 9;            // transform grid
  const int GA = (NN + 31) / 32;     // 1563

  // res = bf16(x @ res_w + res_b)
  resg_k<<<(NN + 63) / 64, 256, 0, stream>>>(xb, BpR, rb, resb);

  // layer 1
  trans_k<<<GT, 256, 0, stream>>>(xb, Bp1, yw);
  aggf_k<1><<<GA, 256, 0, stream>>>(offs, elist, yw, b1, resb, nullptr, h1);
  // layer 2
  trans_k<<<GT, 256, 0, stream>>>(h1, Bp2, yw);
  aggf_k<1><<<GA, 256, 0, stream>>>(offs, elist, yw, b2, resb, nullptr, h2);
  // layer 3
  trans_k<<<GT, 256, 0, stream>>>(h2, Bp3, yw);
  aggf_k<2><<<GA, 256, 0, stream>>>(offs, elist, yw, b3, resb, (float*)d_out, nullptr);
}

// Round 15
// 339.851 us; speedup vs baseline: 1.1778x; 1.1778x over previous
//
#include <hip/hip_runtime.h>
#include <hip/hip_bf16.h>

#define NN 50000
#define EE 600000
#define RR 8
#define NSEG (NN*RR)                     // 400000
#define NB_SCAN ((NSEG + 1023)/1024)     // 391

typedef unsigned int u32;
typedef __attribute__((ext_vector_type(8))) short bf16x8;
typedef __attribute__((ext_vector_type(4))) float f32x4;
typedef __attribute__((ext_vector_type(4))) u32 u32x4;

// fp32 -> bf16 round-to-nearest-even (finite inputs only)
__device__ inline unsigned short f2bf(float f){
  u32 u = __float_as_uint(f);
  u32 r = (u + 0x7fffu + ((u >> 16) & 1u)) >> 16;
  return (unsigned short)r;
}
__device__ inline float bf2f(unsigned short b){ return __uint_as_float((u32)b << 16); }

#define GLD16(g, l)  __builtin_amdgcn_global_load_lds( \
    (const __attribute__((address_space(1))) void*)(g), \
    (__attribute__((address_space(3))) void*)(l), 16, 0, 0)

// ---------------- conversion: fp32 -> bf16, 4 elems/thread ----------------
__global__ void cvt_k(const float* __restrict__ in, unsigned short* __restrict__ out, int n4){
  int i = blockIdx.x * 256 + threadIdx.x;
  if (i >= n4) return;
  float4 v = ((const float4*)in)[i];
  ushort4 o;
  o.x = f2bf(v.x); o.y = f2bf(v.y); o.z = f2bf(v.z); o.w = f2bf(v.w);
  ((ushort4*)out)[i] = o;
}

// ---------------- pack B (W stack) into MFMA fragment order ----------------
// frag id = k32*8 + nf; within frag: lane*8 + i
// element: B[k32*32 + (lane>>4)*8 + i][nf*16 + (lane&15)]
__global__ void pack_k(const float* __restrict__ Wrel, const float* __restrict__ root,
                       short* __restrict__ Bp, int nk32, int krel){
  int tid = blockIdx.x * 256 + threadIdx.x;
  if (tid >= nk32 * 512) return;
  int lane = tid & 63;
  int nf   = (tid >> 6) & 7;
  int k32  = tid >> 9;
  int col  = nf * 16 + (lane & 15);
  short vals[8];
#pragma unroll
  for (int i = 0; i < 8; ++i){
    int kk = k32 * 32 + ((lane >> 4) << 3) + i;
    float f = (kk < krel) ? Wrel[(size_t)kk * 128 + col]
                          : root[(size_t)(kk - krel) * 128 + col];
    vals[i] = (short)f2bf(f);
  }
  *(bf16x8*)(Bp + (size_t)tid * 8) = *(const bf16x8*)vals;
}

// ---------------- CSR build (relation-major: seg = r*NN + dst) -------------
__global__ void count_k(const int* __restrict__ dst, const int* __restrict__ et,
                        u32* __restrict__ cnt){
  int e = blockIdx.x * 256 + threadIdx.x;
  if (e >= EE) return;
  atomicAdd(&cnt[(size_t)et[e] * NN + dst[e]], 1u);
}

__global__ void scan1_k(const u32* __restrict__ cnt, u32* __restrict__ offs, u32* __restrict__ bsum){
  __shared__ u32 s[512];
  int t = threadIdx.x;                       // 256 threads
  int base = blockIdx.x * 1024 + t * 4;
  u32 loc[4]; u32 sum = 0;
#pragma unroll
  for (int i = 0; i < 4; ++i){ loc[i] = (base + i < NSEG) ? cnt[base + i] : 0u; sum += loc[i]; }
  int pb = 0;
  s[t] = sum; __syncthreads();
  for (int off = 1; off < 256; off <<= 1){
    u32 v = s[pb * 256 + t];
    if (t >= off) v += s[pb * 256 + t - off];
    s[(pb ^ 1) * 256 + t] = v; pb ^= 1; __syncthreads();
  }
  u32 incl = s[pb * 256 + t];
  u32 excl = incl - sum;
  if (t == 255) bsum[blockIdx.x] = incl;
  u32 run = excl;
#pragma unroll
  for (int i = 0; i < 4; ++i){ if (base + i < NSEG) offs[base + i] = run; run += loc[i]; }
}

__global__ void scan2_k(u32* __restrict__ bsum){
  __shared__ u32 s[1024];
  int t = threadIdx.x;                       // 512 threads
  u32 v = (t < NB_SCAN) ? bsum[t] : 0u;
  int pb = 0;
  s[t] = v; __syncthreads();
  for (int off = 1; off < 512; off <<= 1){
    u32 x = s[pb * 512 + t];
    if (t >= off) x += s[pb * 512 + t - off];
    s[(pb ^ 1) * 512 + t] = x; pb ^= 1; __syncthreads();
  }
  u32 incl = s[pb * 512 + t];
  if (t < NB_SCAN) bsum[t] = incl - v;       // exclusive
}

__global__ void scan3_k(u32* __restrict__ offs, const u32* __restrict__ bsum){
  int t = threadIdx.x;
  int base = blockIdx.x * 1024 + t * 4;
  u32 add = bsum[blockIdx.x];
#pragma unroll
  for (int i = 0; i < 4; ++i){ if (base + i < NSEG) offs[base + i] += add; }
  if (blockIdx.x == 0 && t == 0) offs[NSEG] = EE;
}

// fill: reuse cnt as cursor (atomicSub)
__global__ void fill_k(const int* __restrict__ src, const int* __restrict__ dst,
                       const int* __restrict__ et, const u32* __restrict__ offs,
                       u32* __restrict__ cnt, int* __restrict__ elist){
  int e = blockIdx.x * 256 + threadIdx.x;
  if (e >= EE) return;
  int s = et[e] * NN + dst[e];
  u32 p = atomicSub(&cnt[s], 1u);
  elist[offs[s] + p - 1] = src[e];
}

// ------- per-(relation,dst) mean aggregation -> a[R][NN][128] bf16 ----------
// 8-lane group per segment, 32 segments/block; lane owns 32 B of the row.
// 4-deep edge batches: 4 independent row loads in flight per group.
#define ACC1(P0, P1) do{ \
  _Pragma("unroll") \
  for (int i_ = 0; i_ < 4; ++i_){ \
    s[2*i_]     += __uint_as_float((P0)[i_] << 16); \
    s[2*i_+1]   += __uint_as_float((P0)[i_] & 0xffff0000u); \
    s[8+2*i_]   += __uint_as_float((P1)[i_] << 16); \
    s[8+2*i_+1] += __uint_as_float((P1)[i_] & 0xffff0000u); \
  } }while(0)

__launch_bounds__(256, 6)
__global__ void agg_k(const u32* __restrict__ offs, const int* __restrict__ elist,
                      const unsigned short* __restrict__ h, unsigned short* __restrict__ a){
  int t = threadIdx.x;
  int g = t >> 3, ll8 = t & 7;
  int seg = blockIdx.x * 32 + g;
  u32 beg = offs[seg], end = offs[seg + 1];
  float s[16];
#pragma unroll
  for (int i = 0; i < 16; ++i) s[i] = 0.f;
  const unsigned short* hb = h + (size_t)ll8 * 16;
  u32 e = beg;
  for (; e + 4 <= end; e += 4){
    int s0 = elist[e], s1 = elist[e+1], s2 = elist[e+2], s3 = elist[e+3];
    const unsigned short* r0 = hb + (size_t)s0 * 128;
    const unsigned short* r1 = hb + (size_t)s1 * 128;
    const unsigned short* r2 = hb + (size_t)s2 * 128;
    const unsigned short* r3 = hb + (size_t)s3 * 128;
    u32x4 p00 = *(const u32x4*)r0, p01 = *(const u32x4*)(r0 + 8);
    u32x4 p10 = *(const u32x4*)r1, p11 = *(const u32x4*)(r1 + 8);
    u32x4 p20 = *(const u32x4*)r2, p21 = *(const u32x4*)(r2 + 8);
    u32x4 p30 = *(const u32x4*)r3, p31 = *(const u32x4*)(r3 + 8);
    ACC1(p00, p01); ACC1(p10, p11); ACC1(p20, p21); ACC1(p30, p31);
  }
  if (e + 2 <= end){
    int s0 = elist[e], s1 = elist[e+1];
    const unsigned short* r0 = hb + (size_t)s0 * 128;
    const unsigned short* r1 = hb + (size_t)s1 * 128;
    u32x4 p00 = *(const u32x4*)r0, p01 = *(const u32x4*)(r0 + 8);
    u32x4 p10 = *(const u32x4*)r1, p11 = *(const u32x4*)(r1 + 8);
    ACC1(p00, p01); ACC1(p10, p11);
    e += 2;
  }
  if (e < end){
    int s0 = elist[e];
    const unsigned short* r0 = hb + (size_t)s0 * 128;
    u32x4 p00 = *(const u32x4*)r0, p01 = *(const u32x4*)(r0 + 8);
    ACC1(p00, p01);
  }
  u32 deg = end - beg;
  if (deg){
    float inv = 1.f / (float)deg;
#pragma unroll
    for (int i = 0; i < 16; ++i) s[i] *= inv;
  }
  u32x4 o0, o1;
#pragma unroll
  for (int i = 0; i < 4; ++i){
    o0[i] = (u32)f2bf(s[2*i])   | ((u32)f2bf(s[2*i+1])   << 16);
    o1[i] = (u32)f2bf(s[8+2*i]) | ((u32)f2bf(s[8+2*i+1]) << 16);
  }
  unsigned short* ap = a + (size_t)seg * 128 + ll8 * 16;
  *(u32x4*)ap = o0;
  *(u32x4*)(ap + 8) = o1;
}

// ---------------- res projection: resb = bf16(x @ res_w + res_b) ----------
__launch_bounds__(256, 4)
__global__ void resg_k(const unsigned short* __restrict__ xb, const short* __restrict__ Bp,
                       const float* __restrict__ rb, unsigned short* __restrict__ resb){
  const int tid = threadIdx.x;
  const int w = tid >> 6, l = tid & 63;
  const int sub = l >> 4, llr = l & 15;
  const int rowbase = blockIdx.x * 64 + w * 16;
  int vr = rowbase + llr; if (vr > NN - 1) vr = NN - 1;
  f32x4 acc[8] = {};
#pragma unroll
  for (int t = 0; t < 4; ++t){
    bf16x8 af = *(const bf16x8*)(xb + (size_t)vr * 128 + (t * 4 + sub) * 8);
    const short* bb = Bp + (size_t)(t * 8) * 512 + l * 8;
#pragma unroll
    for (int nf = 0; nf < 8; ++nf){
      bf16x8 bq = *(const bf16x8*)(bb + nf * 512);
      acc[nf] = __builtin_amdgcn_mfma_f32_16x16x32_bf16(af, bq, acc[nf], 0, 0, 0);
    }
  }
  const int lr = l >> 4, lc = l & 15;
#pragma unroll
  for (int nf = 0; nf < 8; ++nf){
    int col = nf * 16 + lc;
    float bv = rb[col];
#pragma unroll
    for (int r = 0; r < 4; ++r){
      int row = rowbase + lr * 4 + r;
      if (row < NN) resb[(size_t)row * 128 + col] = f2bf(acc[nf][r] + bv);
    }
  }
}

// -------- MFMA GEMM, BM=32: async staging, single buffer, 2 barriers --------
// BM=32, BN=128, BK=64. Grid = 1563 -> ~6 blocks/CU (vs 3 at BM=64): the
// per-kt vmcnt drain overlaps 5 other resident blocks' compute.
// 4 waves: wave (wm,wn) owns 16 rows x 64 cols (acc 4 f32x4).
// LDS: A [8 q][32 row][16B] = 4 KB | B slice packed 16 KB -> 20.5 KB total.
template<int OUTMODE>
__launch_bounds__(256, 6)
__global__ void gemm_k(const unsigned short* __restrict__ Aa,   // [R][NN][128]
                       const unsigned short* __restrict__ Ah,   // [NN][128]
                       const short* __restrict__ Bp,            // 18*8192 shorts packed
                       const float* __restrict__ bias,
                       const unsigned short* __restrict__ resb,
                       float* __restrict__ outf, unsigned short* __restrict__ outb){
  __shared__ short lds[10240];               // A 2048 | B 8192 shorts
  const int tid = threadIdx.x;
  const int w = tid >> 6, l = tid & 63;
  const int wm = w >> 1, wn = w & 1;
  const int sub = l >> 4, llr = l & 15;
  const int mbase = blockIdx.x * 32;
  const size_t plane = (size_t)NN * 128;
  f32x4 acc[4] = {};

  int arow = mbase + (l & 31); if (arow > NN - 1) arow = NN - 1;
  const int aq = w * 2 + (l >> 5);           // this thread's A chunk q (0..7)

#pragma unroll 1
  for (int kt = 0; kt < 18; ++kt){
    const unsigned short* abase = (kt < 16)
        ? Aa + (size_t)(kt >> 1) * plane + (size_t)(kt & 1) * 64
        : Ah + (size_t)(kt - 16) * 64;
    // A-tile: 1 issue/thread; chunk idx = tid -> LDS [q=tid>>5][row=tid&31]
    GLD16(abase + (size_t)arow * 128 + aq * 8, lds + (size_t)(w * 64) * 8);
    // B-slice: 4 issues, contiguous 16 KB of packed fragments
    const short* bsrc = Bp + (size_t)kt * 8192;
#pragma unroll
    for (int i = 0; i < 4; ++i)
      GLD16(bsrc + (size_t)(i * 256 + tid) * 8, lds + (size_t)(2048 + (i * 256 + w * 64) * 8));
    __syncthreads();
#pragma unroll
    for (int t = 0; t < 2; ++t){
      bf16x8 af = *(const bf16x8*)(lds + (size_t)((t * 4 + sub) * 32 + wm * 16 + llr) * 8);
#pragma unroll
      for (int nf = 0; nf < 4; ++nf){
        bf16x8 bq = *(const bf16x8*)(lds + (size_t)(2048 + (t * 8 + wn * 4 + nf) * 512 + l * 8));
        acc[nf] = __builtin_amdgcn_mfma_f32_16x16x32_bf16(af, bq, acc[nf], 0, 0, 0);
      }
    }
    __syncthreads();
  }

  const int lr = l >> 4, lc = l & 15;
#pragma unroll
  for (int nf = 0; nf < 4; ++nf){
    int col = wn * 64 + nf * 16 + lc;
    float bv = bias[col];
#pragma unroll
    for (int r = 0; r < 4; ++r){
      int row = mbase + wm * 16 + lr * 4 + r;
      if (row < NN){
        float v = acc[nf][r] + bv;
        v = bf2f(resb[(size_t)row * 128 + col]) + fmaxf(v, 0.f);
        if (OUTMODE == 1) outb[(size_t)row * 128 + col] = f2bf(v);
        else              outf[(size_t)row * 128 + col] = v;
      }
    }
  }
}

extern "C" void kernel_launch(void* const* d_in, const int* in_sizes, int n_in,
                              void* d_out, int out_size, void* d_ws, size_t ws_size,
                              hipStream_t stream){
  const float* x  = (const float*)d_in[0];
  const int*   ei = (const int*)d_in[1];
  const int*   et = (const int*)d_in[2];
  const float* W1 = (const float*)d_in[3];
  const float* r1 = (const float*)d_in[4];
  const float* b1 = (const float*)d_in[5];
  const float* W2 = (const float*)d_in[6];
  const float* r2 = (const float*)d_in[7];
  const float* b2 = (const float*)d_in[8];
  const float* W3 = (const float*)d_in[9];
  const float* r3 = (const float*)d_in[10];
  const float* b3 = (const float*)d_in[11];
  const float* rw = (const float*)d_in[12];
  const float* rb = (const float*)d_in[13];
  const int* srcv = ei;
  const int* dstv = ei + EE;

  char* p = (char*)d_ws;
  auto take = [&](size_t b)->char*{ char* q = p; p += (b + 255) & ~(size_t)255; return q; };
  unsigned short* a    = (unsigned short*)take((size_t)NN * 1024 * 2);  // [R][NN][128]
  unsigned short* xb   = (unsigned short*)take((size_t)NN * 128 * 2);
  unsigned short* h1   = (unsigned short*)take((size_t)NN * 128 * 2);
  unsigned short* h2   = (unsigned short*)take((size_t)NN * 128 * 2);
  unsigned short* resb = (unsigned short*)take((size_t)NN * 128 * 2);
  short* Bp1 = (short*)take(36 * 4096 * 2);
  short* Bp2 = (short*)take(36 * 4096 * 2);
  short* Bp3 = (short*)take(36 * 4096 * 2);
  short* BpR = (short*)take(4 * 4096 * 2);
  u32* cnt   = (u32*)take((size_t)NSEG * 4);
  u32* offs  = (u32*)take((size_t)(NSEG + 1) * 4);
  int* elist = (int*)take((size_t)EE * 4);
  u32* bsum  = (u32*)take((size_t)NB_SCAN * 4);

  hipMemsetAsync(cnt, 0, (size_t)NSEG * 4, stream);

  // conversions + weight packing (once)
  cvt_k<<<(NN * 128 / 4 + 255) / 256, 256, 0, stream>>>(x, xb, NN * 128 / 4);
  pack_k<<<(36 * 512 + 255) / 256, 256, 0, stream>>>(W1, r1, Bp1, 36, 1024);
  pack_k<<<(36 * 512 + 255) / 256, 256, 0, stream>>>(W2, r2, Bp2, 36, 1024);
  pack_k<<<(36 * 512 + 255) / 256, 256, 0, stream>>>(W3, r3, Bp3, 36, 1024);
  pack_k<<<(4 * 512 + 255) / 256, 256, 0, stream>>>(nullptr, rw, BpR, 4, 0);

  // CSR over segments (etype*NN + dst), once for all layers
  count_k<<<(EE + 255) / 256, 256, 0, stream>>>(dstv, et, cnt);
  scan1_k<<<NB_SCAN, 256, 0, stream>>>(cnt, offs, bsum);
  scan2_k<<<1, 512, 0, stream>>>(bsum);
  scan3_k<<<NB_SCAN, 256, 0, stream>>>(offs, bsum);
  fill_k<<<(EE + 255) / 256, 256, 0, stream>>>(srcv, dstv, et, offs, cnt, elist);

  const int GB = (NN + 31) / 32;  // 1563

  // res = bf16(x @ res_w + res_b)
  resg_k<<<(NN + 63) / 64, 256, 0, stream>>>(xb, BpR, rb, resb);

  // layer 1
  agg_k<<<NSEG / 32, 256, 0, stream>>>(offs, elist, xb, a);
  gemm_k<1><<<GB, 256, 0, stream>>>(a, xb, Bp1, b1, resb, nullptr, h1);
  // layer 2
  agg_k<<<NSEG / 32, 256, 0, stream>>>(offs, elist, h1, a);
  gemm_k<1><<<GB, 256, 0, stream>>>(a, h1, Bp2, b2, resb, nullptr, h2);
  // layer 3
  agg_k<<<NSEG / 32, 256, 0, stream>>>(offs, elist, h2, a);
  gemm_k<2><<<GB, 256, 0, stream>>>(a, h2, Bp3, b3, resb, (float*)d_out, nullptr);
}

// Round 16
// 337.505 us; speedup vs baseline: 1.1860x; 1.0070x over previous
//
#include <hip/hip_runtime.h>
#include <hip/hip_bf16.h>

#define NN 50000
#define EE 600000
#define RR 8
#define NSEG (NN*RR)                     // 400000
#define NB_SCAN ((NSEG + 1023)/1024)     // 391

typedef unsigned int u32;
typedef __attribute__((ext_vector_type(8))) short bf16x8;
typedef __attribute__((ext_vector_type(4))) float f32x4;
typedef __attribute__((ext_vector_type(4))) u32 u32x4;

// fp32 -> bf16 round-to-nearest-even (finite inputs only)
__device__ inline unsigned short f2bf(float f){
  u32 u = __float_as_uint(f);
  u32 r = (u + 0x7fffu + ((u >> 16) & 1u)) >> 16;
  return (unsigned short)r;
}
__device__ inline float bf2f(unsigned short b){ return __uint_as_float((u32)b << 16); }

#define GLD16(g, l)  __builtin_amdgcn_global_load_lds( \
    (const __attribute__((address_space(1))) void*)(g), \
    (__attribute__((address_space(3))) void*)(l), 16, 0, 0)

// ---------------- conversion: fp32 -> bf16, 4 elems/thread ----------------
__global__ void cvt_k(const float* __restrict__ in, unsigned short* __restrict__ out, int n4){
  int i = blockIdx.x * 256 + threadIdx.x;
  if (i >= n4) return;
  float4 v = ((const float4*)in)[i];
  ushort4 o;
  o.x = f2bf(v.x); o.y = f2bf(v.y); o.z = f2bf(v.z); o.w = f2bf(v.w);
  ((ushort4*)out)[i] = o;
}

// ---------------- pack B (W stack) into MFMA fragment order ----------------
// frag id = k32*8 + nf; within frag: lane*8 + i
// element: B[k32*32 + (lane>>4)*8 + i][nf*16 + (lane&15)]
__global__ void pack_k(const float* __restrict__ Wrel, const float* __restrict__ root,
                       short* __restrict__ Bp, int nk32, int krel){
  int tid = blockIdx.x * 256 + threadIdx.x;
  if (tid >= nk32 * 512) return;
  int lane = tid & 63;
  int nf   = (tid >> 6) & 7;
  int k32  = tid >> 9;
  int col  = nf * 16 + (lane & 15);
  short vals[8];
#pragma unroll
  for (int i = 0; i < 8; ++i){
    int kk = k32 * 32 + ((lane >> 4) << 3) + i;
    float f = (kk < krel) ? Wrel[(size_t)kk * 128 + col]
                          : root[(size_t)(kk - krel) * 128 + col];
    vals[i] = (short)f2bf(f);
  }
  *(bf16x8*)(Bp + (size_t)tid * 8) = *(const bf16x8*)vals;
}

// ---------------- CSR build (relation-major: seg = r*NN + dst) -------------
__global__ void count_k(const int* __restrict__ dst, const int* __restrict__ et,
                        u32* __restrict__ cnt){
  int e = blockIdx.x * 256 + threadIdx.x;
  if (e >= EE) return;
  atomicAdd(&cnt[(size_t)et[e] * NN + dst[e]], 1u);
}

__global__ void scan1_k(const u32* __restrict__ cnt, u32* __restrict__ offs, u32* __restrict__ bsum){
  __shared__ u32 s[512];
  int t = threadIdx.x;                       // 256 threads
  int base = blockIdx.x * 1024 + t * 4;
  u32 loc[4]; u32 sum = 0;
#pragma unroll
  for (int i = 0; i < 4; ++i){ loc[i] = (base + i < NSEG) ? cnt[base + i] : 0u; sum += loc[i]; }
  int pb = 0;
  s[t] = sum; __syncthreads();
  for (int off = 1; off < 256; off <<= 1){
    u32 v = s[pb * 256 + t];
    if (t >= off) v += s[pb * 256 + t - off];
    s[(pb ^ 1) * 256 + t] = v; pb ^= 1; __syncthreads();
  }
  u32 incl = s[pb * 256 + t];
  u32 excl = incl - sum;
  if (t == 255) bsum[blockIdx.x] = incl;
  u32 run = excl;
#pragma unroll
  for (int i = 0; i < 4; ++i){ if (base + i < NSEG) offs[base + i] = run; run += loc[i]; }
}

__global__ void scan2_k(u32* __restrict__ bsum){
  __shared__ u32 s[1024];
  int t = threadIdx.x;                       // 512 threads
  u32 v = (t < NB_SCAN) ? bsum[t] : 0u;
  int pb = 0;
  s[t] = v; __syncthreads();
  for (int off = 1; off < 512; off <<= 1){
    u32 x = s[pb * 512 + t];
    if (t >= off) x += s[pb * 512 + t - off];
    s[(pb ^ 1) * 512 + t] = x; pb ^= 1; __syncthreads();
  }
  u32 incl = s[pb * 512 + t];
  if (t < NB_SCAN) bsum[t] = incl - v;       // exclusive
}

__global__ void scan3_k(u32* __restrict__ offs, const u32* __restrict__ bsum){
  int t = threadIdx.x;
  int base = blockIdx.x * 1024 + t * 4;
  u32 add = bsum[blockIdx.x];
#pragma unroll
  for (int i = 0; i < 4; ++i){ if (base + i < NSEG) offs[base + i] += add; }
  if (blockIdx.x == 0 && t == 0) offs[NSEG] = EE;
}

// fill: reuse cnt as cursor (atomicSub)
__global__ void fill_k(const int* __restrict__ src, const int* __restrict__ dst,
                       const int* __restrict__ et, const u32* __restrict__ offs,
                       u32* __restrict__ cnt, int* __restrict__ elist){
  int e = blockIdx.x * 256 + threadIdx.x;
  if (e >= EE) return;
  int s = et[e] * NN + dst[e];
  u32 p = atomicSub(&cnt[s], 1u);
  elist[offs[s] + p - 1] = src[e];
}

// ------- per-(relation,dst) mean aggregation -> a[R][NN][128] bf16 ----------
// 8-lane group per segment, 32 segments/block; lane owns 32 B of the row.
// 4-deep edge batches: 4 independent row loads in flight per group.
#define ACC1(P0, P1) do{ \
  _Pragma("unroll") \
  for (int i_ = 0; i_ < 4; ++i_){ \
    s[2*i_]     += __uint_as_float((P0)[i_] << 16); \
    s[2*i_+1]   += __uint_as_float((P0)[i_] & 0xffff0000u); \
    s[8+2*i_]   += __uint_as_float((P1)[i_] << 16); \
    s[8+2*i_+1] += __uint_as_float((P1)[i_] & 0xffff0000u); \
  } }while(0)

__launch_bounds__(256, 6)
__global__ void agg_k(const u32* __restrict__ offs, const int* __restrict__ elist,
                      const unsigned short* __restrict__ h, unsigned short* __restrict__ a){
  int t = threadIdx.x;
  int g = t >> 3, ll8 = t & 7;
  int seg = blockIdx.x * 32 + g;
  u32 beg = offs[seg], end = offs[seg + 1];
  float s[16];
#pragma unroll
  for (int i = 0; i < 16; ++i) s[i] = 0.f;
  const unsigned short* hb = h + (size_t)ll8 * 16;
  u32 e = beg;
  for (; e + 4 <= end; e += 4){
    int s0 = elist[e], s1 = elist[e+1], s2 = elist[e+2], s3 = elist[e+3];
    const unsigned short* r0 = hb + (size_t)s0 * 128;
    const unsigned short* r1 = hb + (size_t)s1 * 128;
    const unsigned short* r2 = hb + (size_t)s2 * 128;
    const unsigned short* r3 = hb + (size_t)s3 * 128;
    u32x4 p00 = *(const u32x4*)r0, p01 = *(const u32x4*)(r0 + 8);
    u32x4 p10 = *(const u32x4*)r1, p11 = *(const u32x4*)(r1 + 8);
    u32x4 p20 = *(const u32x4*)r2, p21 = *(const u32x4*)(r2 + 8);
    u32x4 p30 = *(const u32x4*)r3, p31 = *(const u32x4*)(r3 + 8);
    ACC1(p00, p01); ACC1(p10, p11); ACC1(p20, p21); ACC1(p30, p31);
  }
  if (e + 2 <= end){
    int s0 = elist[e], s1 = elist[e+1];
    const unsigned short* r0 = hb + (size_t)s0 * 128;
    const unsigned short* r1 = hb + (size_t)s1 * 128;
    u32x4 p00 = *(const u32x4*)r0, p01 = *(const u32x4*)(r0 + 8);
    u32x4 p10 = *(const u32x4*)r1, p11 = *(const u32x4*)(r1 + 8);
    ACC1(p00, p01); ACC1(p10, p11);
    e += 2;
  }
  if (e < end){
    int s0 = elist[e];
    const unsigned short* r0 = hb + (size_t)s0 * 128;
    u32x4 p00 = *(const u32x4*)r0, p01 = *(const u32x4*)(r0 + 8);
    ACC1(p00, p01);
  }
  u32 deg = end - beg;
  if (deg){
    float inv = 1.f / (float)deg;
#pragma unroll
    for (int i = 0; i < 16; ++i) s[i] *= inv;
  }
  u32x4 o0, o1;
#pragma unroll
  for (int i = 0; i < 4; ++i){
    o0[i] = (u32)f2bf(s[2*i])   | ((u32)f2bf(s[2*i+1])   << 16);
    o1[i] = (u32)f2bf(s[8+2*i]) | ((u32)f2bf(s[8+2*i+1]) << 16);
  }
  unsigned short* ap = a + (size_t)seg * 128 + ll8 * 16;
  *(u32x4*)ap = o0;
  *(u32x4*)(ap + 8) = o1;
}

// ---------------- res projection: resb = bf16(x @ res_w + res_b) ----------
__launch_bounds__(256, 4)
__global__ void resg_k(const unsigned short* __restrict__ xb, const short* __restrict__ Bp,
                       const float* __restrict__ rb, unsigned short* __restrict__ resb){
  const int tid = threadIdx.x;
  const int w = tid >> 6, l = tid & 63;
  const int sub = l >> 4, llr = l & 15;
  const int rowbase = blockIdx.x * 64 + w * 16;
  int vr = rowbase + llr; if (vr > NN - 1) vr = NN - 1;
  f32x4 acc[8] = {};
#pragma unroll
  for (int t = 0; t < 4; ++t){
    bf16x8 af = *(const bf16x8*)(xb + (size_t)vr * 128 + (t * 4 + sub) * 8);
    const short* bb = Bp + (size_t)(t * 8) * 512 + l * 8;
#pragma unroll
    for (int nf = 0; nf < 8; ++nf){
      bf16x8 bq = *(const bf16x8*)(bb + nf * 512);
      acc[nf] = __builtin_amdgcn_mfma_f32_16x16x32_bf16(af, bq, acc[nf], 0, 0, 0);
    }
  }
  const int lr = l >> 4, lc = l & 15;
#pragma unroll
  for (int nf = 0; nf < 8; ++nf){
    int col = nf * 16 + lc;
    float bv = rb[col];
#pragma unroll
    for (int r = 0; r < 4; ++r){
      int row = rowbase + lr * 4 + r;
      if (row < NN) resb[(size_t)row * 128 + col] = f2bf(acc[nf][r] + bv);
    }
  }
}

// -------- MFMA GEMM, BM=32: 2-buffer COUNTED-vmcnt pipeline -----------------
// BM=32, BN=128, BK=64; grid 1563; LDS 2 x 20.5 KB -> 3 blocks/CU.
// Per kt: STAGE(kt+1) -> vmcnt(5) (kt's 5 loads landed; kt+1's 5 REMAIN IN
// FLIGHT through barrier+compute) -> raw barrier -> 8 MFMA -> lgkmcnt(0)
// -> raw barrier (WAR fence). Load latency overlaps compute instead of
// serializing with it (the R9/R15 47.5us invariant).
template<int OUTMODE>
__launch_bounds__(256, 3)
__global__ void gemm_k(const unsigned short* __restrict__ Aa,   // [R][NN][128]
                       const unsigned short* __restrict__ Ah,   // [NN][128]
                       const short* __restrict__ Bp,            // 18*8192 shorts packed
                       const float* __restrict__ bias,
                       const unsigned short* __restrict__ resb,
                       float* __restrict__ outf, unsigned short* __restrict__ outb){
  __shared__ short lds[2][10240];            // per buf: A 2048 | B 8192 shorts
  const int tid = threadIdx.x;
  const int w = tid >> 6, l = tid & 63;
  const int wm = w >> 1, wn = w & 1;
  const int sub = l >> 4, llr = l & 15;
  const int mbase = blockIdx.x * 32;
  const size_t plane = (size_t)NN * 128;
  f32x4 acc[4] = {};

  int arow = mbase + (l & 31); if (arow > NN - 1) arow = NN - 1;
  const int aq = w * 2 + (l >> 5);           // this thread's A chunk q (0..7)

#define STAGE(kt, b) do{ \
    const unsigned short* abase_ = ((kt) < 16) \
        ? Aa + (size_t)((kt) >> 1) * plane + (size_t)((kt) & 1) * 64 \
        : Ah + (size_t)((kt) - 16) * 64; \
    GLD16(abase_ + (size_t)arow * 128 + aq * 8, &lds[b][(size_t)(w * 64) * 8]); \
    const short* bsrc_ = Bp + (size_t)(kt) * 8192; \
    _Pragma("unroll") \
    for (int i_ = 0; i_ < 4; ++i_) \
      GLD16(bsrc_ + (size_t)(i_ * 256 + tid) * 8, \
            &lds[b][(size_t)(2048 + (i_ * 256 + w * 64) * 8)]); \
  }while(0)

  STAGE(0, 0);

#pragma unroll
  for (int kt = 0; kt < 18; ++kt){
    if (kt + 1 < 18) STAGE(kt + 1, (kt + 1) & 1);
    __builtin_amdgcn_sched_barrier(0);
    if (kt + 1 < 18) asm volatile("s_waitcnt vmcnt(5)" ::: "memory");
    else             asm volatile("s_waitcnt vmcnt(0)" ::: "memory");
    __builtin_amdgcn_sched_barrier(0);
    __builtin_amdgcn_s_barrier();            // tile kt visible to all waves
    const short* lb = lds[kt & 1];
#pragma unroll
    for (int t = 0; t < 2; ++t){
      bf16x8 af = *(const bf16x8*)(lb + (size_t)((t * 4 + sub) * 32 + wm * 16 + llr) * 8);
#pragma unroll
      for (int nf = 0; nf < 4; ++nf){
        bf16x8 bq = *(const bf16x8*)(lb + (size_t)(2048 + (t * 8 + wn * 4 + nf) * 512 + l * 8));
        acc[nf] = __builtin_amdgcn_mfma_f32_16x16x32_bf16(af, bq, acc[nf], 0, 0, 0);
      }
    }
    asm volatile("s_waitcnt lgkmcnt(0)" ::: "memory");   // LDS reads done
    __builtin_amdgcn_sched_barrier(0);
    __builtin_amdgcn_s_barrier();            // WAR fence before buffer reuse
  }
#undef STAGE

  const int lr = l >> 4, lc = l & 15;
#pragma unroll
  for (int nf = 0; nf < 4; ++nf){
    int col = wn * 64 + nf * 16 + lc;
    float bv = bias[col];
#pragma unroll
    for (int r = 0; r < 4; ++r){
      int row = mbase + wm * 16 + lr * 4 + r;
      if (row < NN){
        float v = acc[nf][r] + bv;
        v = bf2f(resb[(size_t)row * 128 + col]) + fmaxf(v, 0.f);
        if (OUTMODE == 1) outb[(size_t)row * 128 + col] = f2bf(v);
        else              outf[(size_t)row * 128 + col] = v;
      }
    }
  }
}

extern "C" void kernel_launch(void* const* d_in, const int* in_sizes, int n_in,
                              void* d_out, int out_size, void* d_ws, size_t ws_size,
                              hipStream_t stream){
  const float* x  = (const float*)d_in[0];
  const int*   ei = (const int*)d_in[1];
  const int*   et = (const int*)d_in[2];
  const float* W1 = (const float*)d_in[3];
  const float* r1 = (const float*)d_in[4];
  const float* b1 = (const float*)d_in[5];
  const float* W2 = (const float*)d_in[6];
  const float* r2 = (const float*)d_in[7];
  const float* b2 = (const float*)d_in[8];
  const float* W3 = (const float*)d_in[9];
  const float* r3 = (const float*)d_in[10];
  const float* b3 = (const float*)d_in[11];
  const float* rw = (const float*)d_in[12];
  const float* rb = (const float*)d_in[13];
  const int* srcv = ei;
  const int* dstv = ei + EE;

  char* p = (char*)d_ws;
  auto take = [&](size_t b)->char*{ char* q = p; p += (b + 255) & ~(size_t)255; return q; };
  unsigned short* a    = (unsigned short*)take((size_t)NN * 1024 * 2);  // [R][NN][128]
  unsigned short* xb   = (unsigned short*)take((size_t)NN * 128 * 2);
  unsigned short* h1   = (unsigned short*)take((size_t)NN * 128 * 2);
  unsigned short* h2   = (unsigned short*)take((size_t)NN * 128 * 2);
  unsigned short* resb = (unsigned short*)take((size_t)NN * 128 * 2);
  short* Bp1 = (short*)take(36 * 4096 * 2);
  short* Bp2 = (short*)take(36 * 4096 * 2);
  short* Bp3 = (short*)take(36 * 4096 * 2);
  short* BpR = (short*)take(4 * 4096 * 2);
  u32* cnt   = (u32*)take((size_t)NSEG * 4);
  u32* offs  = (u32*)take((size_t)(NSEG + 1) * 4);
  int* elist = (int*)take((size_t)EE * 4);
  u32* bsum  = (u32*)take((size_t)NB_SCAN * 4);

  hipMemsetAsync(cnt, 0, (size_t)NSEG * 4, stream);

  // conversions + weight packing (once)
  cvt_k<<<(NN * 128 / 4 + 255) / 256, 256, 0, stream>>>(x, xb, NN * 128 / 4);
  pack_k<<<(36 * 512 + 255) / 256, 256, 0, stream>>>(W1, r1, Bp1, 36, 1024);
  pack_k<<<(36 * 512 + 255) / 256, 256, 0, stream>>>(W2, r2, Bp2, 36, 1024);
  pack_k<<<(36 * 512 + 255) / 256, 256, 0, stream>>>(W3, r3, Bp3, 36, 1024);
  pack_k<<<(4 * 512 + 255) / 256, 256, 0, stream>>>(nullptr, rw, BpR, 4, 0);

  // CSR over segments (etype*NN + dst), once for all layers
  count_k<<<(EE + 255) / 256, 256, 0, stream>>>(dstv, et, cnt);
  scan1_k<<<NB_SCAN, 256, 0, stream>>>(cnt, offs, bsum);
  scan2_k<<<1, 512, 0, stream>>>(bsum);
  scan3_k<<<NB_SCAN, 256, 0, stream>>>(offs, bsum);
  fill_k<<<(EE + 255) / 256, 256, 0, stream>>>(srcv, dstv, et, offs, cnt, elist);

  const int GB = (NN + 31) / 32;  // 1563

  // res = bf16(x @ res_w + res_b)
  resg_k<<<(NN + 63) / 64, 256, 0, stream>>>(xb, BpR, rb, resb);

  // layer 1
  agg_k<<<NSEG / 32, 256, 0, stream>>>(offs, elist, xb, a);
  gemm_k<1><<<GB, 256, 0, stream>>>(a, xb, Bp1, b1, resb, nullptr, h1);
  // layer 2
  agg_k<<<NSEG / 32, 256, 0, stream>>>(offs, elist, h1, a);
  gemm_k<1><<<GB, 256, 0, stream>>>(a, h1, Bp2, b2, resb, nullptr, h2);
  // layer 3
  agg_k<<<NSEG / 32, 256, 0, stream>>>(offs, elist, h2, a);
  gemm_k<2><<<GB, 256, 0, stream>>>(a, h2, Bp3, b3, resb, (float*)d_out, nullptr);
}

// Round 17
// 316.610 us; speedup vs baseline: 1.2643x; 1.0660x over previous
//
#include <hip/hip_runtime.h>
#include <hip/hip_bf16.h>

#define NN 50000
#define EE 600000
#define RR 8
#define NSEG (NN*RR)                     // 400000
#define NB_SCAN ((NSEG + 1023)/1024)     // 391

typedef unsigned int u32;
typedef __attribute__((ext_vector_type(8))) short bf16x8;
typedef __attribute__((ext_vector_type(4))) float f32x4;
typedef __attribute__((ext_vector_type(4))) u32 u32x4;

// fp32 -> bf16 round-to-nearest-even (finite inputs only)
__device__ inline unsigned short f2bf(float f){
  u32 u = __float_as_uint(f);
  u32 r = (u + 0x7fffu + ((u >> 16) & 1u)) >> 16;
  return (unsigned short)r;
}
__device__ inline float bf2f(unsigned short b){ return __uint_as_float((u32)b << 16); }

#define GLD16(g, l)  __builtin_amdgcn_global_load_lds( \
    (const __attribute__((address_space(1))) void*)(g), \
    (__attribute__((address_space(3))) void*)(l), 16, 0, 0)

// ---------------- conversion: fp32 -> bf16, 4 elems/thread ----------------
__global__ void cvt_k(const float* __restrict__ in, unsigned short* __restrict__ out, int n4){
  int i = blockIdx.x * 256 + threadIdx.x;
  if (i >= n4) return;
  float4 v = ((const float4*)in)[i];
  ushort4 o;
  o.x = f2bf(v.x); o.y = f2bf(v.y); o.z = f2bf(v.z); o.w = f2bf(v.w);
  ((ushort4*)out)[i] = o;
}

// ---------------- pack B (W stack) into MFMA fragment order ----------------
// frag id = k32*8 + nf; within frag: lane*8 + i
// element: B[k32*32 + (lane>>4)*8 + i][nf*16 + (lane&15)]
__global__ void pack_k(const float* __restrict__ Wrel, const float* __restrict__ root,
                       short* __restrict__ Bp, int nk32, int krel){
  int tid = blockIdx.x * 256 + threadIdx.x;
  if (tid >= nk32 * 512) return;
  int lane = tid & 63;
  int nf   = (tid >> 6) & 7;
  int k32  = tid >> 9;
  int col  = nf * 16 + (lane & 15);
  short vals[8];
#pragma unroll
  for (int i = 0; i < 8; ++i){
    int kk = k32 * 32 + ((lane >> 4) << 3) + i;
    float f = (kk < krel) ? Wrel[(size_t)kk * 128 + col]
                          : root[(size_t)(kk - krel) * 128 + col];
    vals[i] = (short)f2bf(f);
  }
  *(bf16x8*)(Bp + (size_t)tid * 8) = *(const bf16x8*)vals;
}

// ---------------- CSR build (relation-major: seg = r*NN + dst) -------------
__global__ void count_k(const int* __restrict__ dst, const int* __restrict__ et,
                        u32* __restrict__ cnt){
  int e = blockIdx.x * 256 + threadIdx.x;
  if (e >= EE) return;
  atomicAdd(&cnt[(size_t)et[e] * NN + dst[e]], 1u);
}

__global__ void scan1_k(const u32* __restrict__ cnt, u32* __restrict__ offs, u32* __restrict__ bsum){
  __shared__ u32 s[512];
  int t = threadIdx.x;                       // 256 threads
  int base = blockIdx.x * 1024 + t * 4;
  u32 loc[4]; u32 sum = 0;
#pragma unroll
  for (int i = 0; i < 4; ++i){ loc[i] = (base + i < NSEG) ? cnt[base + i] : 0u; sum += loc[i]; }
  int pb = 0;
  s[t] = sum; __syncthreads();
  for (int off = 1; off < 256; off <<= 1){
    u32 v = s[pb * 256 + t];
    if (t >= off) v += s[pb * 256 + t - off];
    s[(pb ^ 1) * 256 + t] = v; pb ^= 1; __syncthreads();
  }
  u32 incl = s[pb * 256 + t];
  u32 excl = incl - sum;
  if (t == 255) bsum[blockIdx.x] = incl;
  u32 run = excl;
#pragma unroll
  for (int i = 0; i < 4; ++i){ if (base + i < NSEG) offs[base + i] = run; run += loc[i]; }
}

__global__ void scan2_k(u32* __restrict__ bsum){
  __shared__ u32 s[1024];
  int t = threadIdx.x;                       // 512 threads
  u32 v = (t < NB_SCAN) ? bsum[t] : 0u;
  int pb = 0;
  s[t] = v; __syncthreads();
  for (int off = 1; off < 512; off <<= 1){
    u32 x = s[pb * 512 + t];
    if (t >= off) x += s[pb * 512 + t - off];
    s[(pb ^ 1) * 512 + t] = x; pb ^= 1; __syncthreads();
  }
  u32 incl = s[pb * 512 + t];
  if (t < NB_SCAN) bsum[t] = incl - v;       // exclusive
}

__global__ void scan3_k(u32* __restrict__ offs, const u32* __restrict__ bsum){
  int t = threadIdx.x;
  int base = blockIdx.x * 1024 + t * 4;
  u32 add = bsum[blockIdx.x];
#pragma unroll
  for (int i = 0; i < 4; ++i){ if (base + i < NSEG) offs[base + i] += add; }
  if (blockIdx.x == 0 && t == 0) offs[NSEG] = EE;
}

// fill: reuse cnt as cursor (atomicSub)
__global__ void fill_k(const int* __restrict__ src, const int* __restrict__ dst,
                       const int* __restrict__ et, const u32* __restrict__ offs,
                       u32* __restrict__ cnt, int* __restrict__ elist){
  int e = blockIdx.x * 256 + threadIdx.x;
  if (e >= EE) return;
  int s = et[e] * NN + dst[e];
  u32 p = atomicSub(&cnt[s], 1u);
  elist[offs[s] + p - 1] = src[e];
}

// ---------------- res projection: resb = bf16(x @ res_w + res_b) ----------
__launch_bounds__(256, 4)
__global__ void resg_k(const unsigned short* __restrict__ xb, const short* __restrict__ Bp,
                       const float* __restrict__ rb, unsigned short* __restrict__ resb){
  const int tid = threadIdx.x;
  const int w = tid >> 6, l = tid & 63;
  const int sub = l >> 4, llr = l & 15;
  const int rowbase = blockIdx.x * 64 + w * 16;
  int vr = rowbase + llr; if (vr > NN - 1) vr = NN - 1;
  f32x4 acc[8] = {};
#pragma unroll
  for (int t = 0; t < 4; ++t){
    bf16x8 af = *(const bf16x8*)(xb + (size_t)vr * 128 + (t * 4 + sub) * 8);
    const short* bb = Bp + (size_t)(t * 8) * 512 + l * 8;
#pragma unroll
    for (int nf = 0; nf < 8; ++nf){
      bf16x8 bq = *(const bf16x8*)(bb + nf * 512);
      acc[nf] = __builtin_amdgcn_mfma_f32_16x16x32_bf16(af, bq, acc[nf], 0, 0, 0);
    }
  }
  const int lr = l >> 4, lc = l & 15;
#pragma unroll
  for (int nf = 0; nf < 8; ++nf){
    int col = nf * 16 + lc;
    float bv = rb[col];
#pragma unroll
    for (int r = 0; r < 4; ++r){
      int row = rowbase + lr * 4 + r;
      if (row < NN) resb[(size_t)row * 128 + col] = f2bf(acc[nf][r] + bv);
    }
  }
}

// -------- FUSED layer: gather->LDS A-tile (K=1152) -> barrier -> GEMM -------
// 512 threads, BM=32 rows. A-tile [32 rows][1152 cols] bf16 = 72 KB LDS,
// 16B-slot XOR swizzle (slot ^= row&7) for conflict-optimal b128 access.
// Phase 1: 64 8-lane groups x 4 (row,relation) segments (agg_k's pattern) +
// root-row copies. Phase 2: wave w owns 32 rows x cols [16w,16w+16);
// K-loop: NO barriers, NO staging — 4 ds_read + 2 L2-hot B loads + 4 MFMA/kt.
#define ACC1(P0, P1) do{ \
  _Pragma("unroll") \
  for (int i_ = 0; i_ < 4; ++i_){ \
    s[2*i_]     += __uint_as_float((P0)[i_] << 16); \
    s[2*i_+1]   += __uint_as_float((P0)[i_] & 0xffff0000u); \
    s[8+2*i_]   += __uint_as_float((P1)[i_] << 16); \
    s[8+2*i_+1] += __uint_as_float((P1)[i_] & 0xffff0000u); \
  } }while(0)

template<int OUTMODE>
__launch_bounds__(512, 4)
__global__ void fused_k(const u32* __restrict__ offs, const int* __restrict__ elist,
                        const unsigned short* __restrict__ h,
                        const short* __restrict__ Bp,
                        const float* __restrict__ bias,
                        const unsigned short* __restrict__ resb,
                        float* __restrict__ outf, unsigned short* __restrict__ outb){
  __shared__ short A[32 * 1152];             // 72 KB; row stride 2304 B = 144 slots
  char* Ab = (char*)A;
  const int tid = threadIdx.x;
  const int mbase = blockIdx.x * 32;

  // ---------- phase 1: gather ----------
  {
    const int g = tid >> 3, ll8 = tid & 7;
    const unsigned short* hb = h + (size_t)ll8 * 16;
#pragma unroll 1
    for (int j = 0; j < 5; ++j){
      int task = j * 64 + g;
      if (task < 256){
        int r = task >> 5, row = task & 31;
        int v = mbase + row; if (v > NN - 1) v = NN - 1;
        size_t seg = (size_t)r * NN + v;
        u32 beg = offs[seg], end = offs[seg + 1];
        float s[16];
#pragma unroll
        for (int i = 0; i < 16; ++i) s[i] = 0.f;
        u32 e = beg;
        for (; e + 4 <= end; e += 4){
          int s0 = elist[e], s1 = elist[e+1], s2 = elist[e+2], s3 = elist[e+3];
          const unsigned short* r0 = hb + (size_t)s0 * 128;
          const unsigned short* r1 = hb + (size_t)s1 * 128;
          const unsigned short* r2 = hb + (size_t)s2 * 128;
          const unsigned short* r3 = hb + (size_t)s3 * 128;
          u32x4 p00 = *(const u32x4*)r0, p01 = *(const u32x4*)(r0 + 8);
          u32x4 p10 = *(const u32x4*)r1, p11 = *(const u32x4*)(r1 + 8);
          u32x4 p20 = *(const u32x4*)r2, p21 = *(const u32x4*)(r2 + 8);
          u32x4 p30 = *(const u32x4*)r3, p31 = *(const u32x4*)(r3 + 8);
          ACC1(p00, p01); ACC1(p10, p11); ACC1(p20, p21); ACC1(p30, p31);
        }
        if (e + 2 <= end){
          int s0 = elist[e], s1 = elist[e+1];
          const unsigned short* r0 = hb + (size_t)s0 * 128;
          const unsigned short* r1 = hb + (size_t)s1 * 128;
          u32x4 p00 = *(const u32x4*)r0, p01 = *(const u32x4*)(r0 + 8);
          u32x4 p10 = *(const u32x4*)r1, p11 = *(const u32x4*)(r1 + 8);
          ACC1(p00, p01); ACC1(p10, p11);
          e += 2;
        }
        if (e < end){
          int s0 = elist[e];
          const unsigned short* r0 = hb + (size_t)s0 * 128;
          u32x4 p00 = *(const u32x4*)r0, p01 = *(const u32x4*)(r0 + 8);
          ACC1(p00, p01);
        }
        u32 deg = end - beg;
        if (deg){
          float inv = 1.f / (float)deg;
#pragma unroll
          for (int i = 0; i < 16; ++i) s[i] *= inv;
        }
        u32x4 o0, o1;
#pragma unroll
        for (int i = 0; i < 4; ++i){
          o0[i] = (u32)f2bf(s[2*i])   | ((u32)f2bf(s[2*i+1])   << 16);
          o1[i] = (u32)f2bf(s[8+2*i]) | ((u32)f2bf(s[8+2*i+1]) << 16);
        }
        int k = row & 7;
        int sl = r * 16 + ll8 * 2;
        *(u32x4*)(Ab + row * 2304 + ((sl    ) ^ k) * 16) = o0;
        *(u32x4*)(Ab + row * 2304 + ((sl + 1) ^ k) * 16) = o1;
      } else if (task < 288){
        int row = task - 256;
        int v = mbase + row; if (v > NN - 1) v = NN - 1;
        const unsigned short* rp = h + (size_t)v * 128 + ll8 * 16;
        u32x4 o0 = *(const u32x4*)rp, o1 = *(const u32x4*)(rp + 8);
        int k = row & 7;
        int sl = 128 + ll8 * 2;
        *(u32x4*)(Ab + row * 2304 + ((sl    ) ^ k) * 16) = o0;
        *(u32x4*)(Ab + row * 2304 + ((sl + 1) ^ k) * 16) = o1;
      }
    }
  }
  __syncthreads();

  // ---------- phase 2: GEMM ----------
  const int w = tid >> 6, l = tid & 63;
  const int sub = l >> 4, llr = l & 15;
  f32x4 acc[2] = {};
  const int k0 = llr & 7, k1 = (16 + llr) & 7;   // == llr&7 both, kept explicit
#pragma unroll 6
  for (int kt = 0; kt < 18; ++kt){
#pragma unroll
    for (int t = 0; t < 2; ++t){
      int ks = kt * 8 + t * 4 + sub;
      bf16x8 af0 = *(const bf16x8*)(Ab + llr * 2304        + (ks ^ k0) * 16);
      bf16x8 af1 = *(const bf16x8*)(Ab + (16 + llr) * 2304 + (ks ^ k1) * 16);
      bf16x8 bq = *(const bf16x8*)(Bp + ((size_t)((kt * 2 + t) * 8 + w)) * 512 + l * 8);
      acc[0] = __builtin_amdgcn_mfma_f32_16x16x32_bf16(af0, bq, acc[0], 0, 0, 0);
      acc[1] = __builtin_amdgcn_mfma_f32_16x16x32_bf16(af1, bq, acc[1], 0, 0, 0);
    }
  }

  // ---------- epilogue ----------
  const int lr = l >> 4, lc = l & 15;
  int col = w * 16 + lc;
  float bv = bias[col];
#pragma unroll
  for (int mf = 0; mf < 2; ++mf){
#pragma unroll
    for (int r = 0; r < 4; ++r){
      int row = mbase + mf * 16 + lr * 4 + r;
      if (row < NN){
        float v = acc[mf][r] + bv;
        v = bf2f(resb[(size_t)row * 128 + col]) + fmaxf(v, 0.f);
        if (OUTMODE == 1) outb[(size_t)row * 128 + col] = f2bf(v);
        else              outf[(size_t)row * 128 + col] = v;
      }
    }
  }
}

extern "C" void kernel_launch(void* const* d_in, const int* in_sizes, int n_in,
                              void* d_out, int out_size, void* d_ws, size_t ws_size,
                              hipStream_t stream){
  const float* x  = (const float*)d_in[0];
  const int*   ei = (const int*)d_in[1];
  const int*   et = (const int*)d_in[2];
  const float* W1 = (const float*)d_in[3];
  const float* r1 = (const float*)d_in[4];
  const float* b1 = (const float*)d_in[5];
  const float* W2 = (const float*)d_in[6];
  const float* r2 = (const float*)d_in[7];
  const float* b2 = (const float*)d_in[8];
  const float* W3 = (const float*)d_in[9];
  const float* r3 = (const float*)d_in[10];
  const float* b3 = (const float*)d_in[11];
  const float* rw = (const float*)d_in[12];
  const float* rb = (const float*)d_in[13];
  const int* srcv = ei;
  const int* dstv = ei + EE;

  char* p = (char*)d_ws;
  auto take = [&](size_t b)->char*{ char* q = p; p += (b + 255) & ~(size_t)255; return q; };
  unsigned short* xb   = (unsigned short*)take((size_t)NN * 128 * 2);
  unsigned short* h1   = (unsigned short*)take((size_t)NN * 128 * 2);
  unsigned short* h2   = (unsigned short*)take((size_t)NN * 128 * 2);
  unsigned short* resb = (unsigned short*)take((size_t)NN * 128 * 2);
  short* Bp1 = (short*)take(36 * 4096 * 2);
  short* Bp2 = (short*)take(36 * 4096 * 2);
  short* Bp3 = (short*)take(36 * 4096 * 2);
  short* BpR = (short*)take(4 * 4096 * 2);
  u32* cnt   = (u32*)take((size_t)NSEG * 4);
  u32* offs  = (u32*)take((size_t)(NSEG + 1) * 4);
  int* elist = (int*)take((size_t)EE * 4);
  u32* bsum  = (u32*)take((size_t)NB_SCAN * 4);

  hipMemsetAsync(cnt, 0, (size_t)NSEG * 4, stream);

  // conversions + weight packing (once)
  cvt_k<<<(NN * 128 / 4 + 255) / 256, 256, 0, stream>>>(x, xb, NN * 128 / 4);
  pack_k<<<(36 * 512 + 255) / 256, 256, 0, stream>>>(W1, r1, Bp1, 36, 1024);
  pack_k<<<(36 * 512 + 255) / 256, 256, 0, stream>>>(W2, r2, Bp2, 36, 1024);
  pack_k<<<(36 * 512 + 255) / 256, 256, 0, stream>>>(W3, r3, Bp3, 36, 1024);
  pack_k<<<(4 * 512 + 255) / 256, 256, 0, stream>>>(nullptr, rw, BpR, 4, 0);

  // CSR over segments (etype*NN + dst), once for all layers
  count_k<<<(EE + 255) / 256, 256, 0, stream>>>(dstv, et, cnt);
  scan1_k<<<NB_SCAN, 256, 0, stream>>>(cnt, offs, bsum);
  scan2_k<<<1, 512, 0, stream>>>(bsum);
  scan3_k<<<NB_SCAN, 256, 0, stream>>>(offs, bsum);
  fill_k<<<(EE + 255) / 256, 256, 0, stream>>>(srcv, dstv, et, offs, cnt, elist);

  const int GB = (NN + 31) / 32;  // 1563

  // res = bf16(x @ res_w + res_b)
  resg_k<<<(NN + 63) / 64, 256, 0, stream>>>(xb, BpR, rb, resb);

  // fused layers
  fused_k<1><<<GB, 512, 0, stream>>>(offs, elist, xb, Bp1, b1, resb, nullptr, h1);
  fused_k<1><<<GB, 512, 0, stream>>>(offs, elist, h1, Bp2, b2, resb, nullptr, h2);
  fused_k<2><<<GB, 512, 0, stream>>>(offs, elist, h2, Bp3, b3, resb, (float*)d_out, nullptr);
}

// Round 18
// 309.845 us; speedup vs baseline: 1.2919x; 1.0218x over previous
//
#include <hip/hip_runtime.h>
#include <hip/hip_bf16.h>

#define NN 50000
#define EE 600000
#define RR 8
#define NSEG (NN*RR)                     // 400000
#define NB_SCAN ((NSEG + 1023)/1024)     // 391
#define RSTRIDE 2320                     // A-tile row stride in BYTES (pad +16 -> bank rot 4/row)

typedef unsigned int u32;
typedef __attribute__((ext_vector_type(8))) short bf16x8;
typedef __attribute__((ext_vector_type(4))) float f32x4;
typedef __attribute__((ext_vector_type(4))) u32 u32x4;

// fp32 -> bf16 round-to-nearest-even (finite inputs only)
__device__ inline unsigned short f2bf(float f){
  u32 u = __float_as_uint(f);
  u32 r = (u + 0x7fffu + ((u >> 16) & 1u)) >> 16;
  return (unsigned short)r;
}
__device__ inline float bf2f(unsigned short b){ return __uint_as_float((u32)b << 16); }

// ---------------- conversion: fp32 -> bf16, 4 elems/thread ----------------
__global__ void cvt_k(const float* __restrict__ in, unsigned short* __restrict__ out, int n4){
  int i = blockIdx.x * 256 + threadIdx.x;
  if (i >= n4) return;
  float4 v = ((const float4*)in)[i];
  ushort4 o;
  o.x = f2bf(v.x); o.y = f2bf(v.y); o.z = f2bf(v.z); o.w = f2bf(v.w);
  ((ushort4*)out)[i] = o;
}

// ---------------- pack ALL B stacks into MFMA fragment order ---------------
// unit = global k32 index: 0-35 Bp1, 36-71 Bp2, 72-107 Bp3, 108-111 BpR.
__global__ void packall_k(const float* __restrict__ W1, const float* __restrict__ r1,
                          const float* __restrict__ W2, const float* __restrict__ r2,
                          const float* __restrict__ W3, const float* __restrict__ r3,
                          const float* __restrict__ rw,
                          short* __restrict__ Bp1, short* __restrict__ Bp2,
                          short* __restrict__ Bp3, short* __restrict__ BpR){
  int tid = blockIdx.x * 256 + threadIdx.x;
  if (tid >= 112 * 512) return;
  int unit = tid >> 9;
  const float* Wrel; const float* root; short* Bp; int k32; int krel;
  if      (unit < 36){ Wrel = W1; root = r1; Bp = Bp1; k32 = unit;       krel = 1024; }
  else if (unit < 72){ Wrel = W2; root = r2; Bp = Bp2; k32 = unit - 36;  krel = 1024; }
  else if (unit <108){ Wrel = W3; root = r3; Bp = Bp3; k32 = unit - 72;  krel = 1024; }
  else               { Wrel = rw; root = rw; Bp = BpR; k32 = unit - 108; krel = 0;    }
  int lane = tid & 63;
  int nf   = (tid >> 6) & 7;
  int col  = nf * 16 + (lane & 15);
  short vals[8];
#pragma unroll
  for (int i = 0; i < 8; ++i){
    int kk = k32 * 32 + ((lane >> 4) << 3) + i;
    float f = (kk < krel) ? Wrel[(size_t)kk * 128 + col]
                          : root[(size_t)(kk - krel) * 128 + col];
    vals[i] = (short)f2bf(f);
  }
  *(bf16x8*)(Bp + (size_t)(k32 * 512 + (tid & 511)) * 8) = *(const bf16x8*)vals;
}

// ---------------- CSR build (relation-major: seg = r*NN + dst) -------------
__global__ void count_k(const int* __restrict__ dst, const int* __restrict__ et,
                        u32* __restrict__ cnt){
  int e = blockIdx.x * 256 + threadIdx.x;
  if (e >= EE) return;
  atomicAdd(&cnt[(size_t)et[e] * NN + dst[e]], 1u);
}

__global__ void scan1_k(const u32* __restrict__ cnt, u32* __restrict__ offs, u32* __restrict__ bsum){
  __shared__ u32 s[512];
  int t = threadIdx.x;                       // 256 threads
  int base = blockIdx.x * 1024 + t * 4;
  u32 loc[4]; u32 sum = 0;
#pragma unroll
  for (int i = 0; i < 4; ++i){ loc[i] = (base + i < NSEG) ? cnt[base + i] : 0u; sum += loc[i]; }
  int pb = 0;
  s[t] = sum; __syncthreads();
  for (int off = 1; off < 256; off <<= 1){
    u32 v = s[pb * 256 + t];
    if (t >= off) v += s[pb * 256 + t - off];
    s[(pb ^ 1) * 256 + t] = v; pb ^= 1; __syncthreads();
  }
  u32 incl = s[pb * 256 + t];
  u32 excl = incl - sum;
  if (t == 255) bsum[blockIdx.x] = incl;
  u32 run = excl;
#pragma unroll
  for (int i = 0; i < 4; ++i){ if (base + i < NSEG) offs[base + i] = run; run += loc[i]; }
}

__global__ void scan2_k(u32* __restrict__ bsum){
  __shared__ u32 s[1024];
  int t = threadIdx.x;                       // 512 threads
  u32 v = (t < NB_SCAN) ? bsum[t] : 0u;
  int pb = 0;
  s[t] = v; __syncthreads();
  for (int off = 1; off < 512; off <<= 1){
    u32 x = s[pb * 512 + t];
    if (t >= off) x += s[pb * 512 + t - off];
    s[(pb ^ 1) * 512 + t] = x; pb ^= 1; __syncthreads();
  }
  u32 incl = s[pb * 512 + t];
  if (t < NB_SCAN) bsum[t] = incl - v;       // exclusive
}

__global__ void scan3_k(u32* __restrict__ offs, const u32* __restrict__ bsum){
  int t = threadIdx.x;
  int base = blockIdx.x * 1024 + t * 4;
  u32 add = bsum[blockIdx.x];
#pragma unroll
  for (int i = 0; i < 4; ++i){ if (base + i < NSEG) offs[base + i] += add; }
  if (blockIdx.x == 0 && t == 0) offs[NSEG] = EE;
}

// fill: reuse cnt as cursor (atomicSub)
__global__ void fill_k(const int* __restrict__ src, const int* __restrict__ dst,
                       const int* __restrict__ et, const u32* __restrict__ offs,
                       u32* __restrict__ cnt, int* __restrict__ elist){
  int e = blockIdx.x * 256 + threadIdx.x;
  if (e >= EE) return;
  int s = et[e] * NN + dst[e];
  u32 p = atomicSub(&cnt[s], 1u);
  elist[offs[s] + p - 1] = src[e];
}

// ---------------- res projection: resb = bf16(x @ res_w + res_b) ----------
__launch_bounds__(256, 4)
__global__ void resg_k(const unsigned short* __restrict__ xb, const short* __restrict__ Bp,
                       const float* __restrict__ rb, unsigned short* __restrict__ resb){
  const int tid = threadIdx.x;
  const int w = tid >> 6, l = tid & 63;
  const int sub = l >> 4, llr = l & 15;
  const int rowbase = blockIdx.x * 64 + w * 16;
  int vr = rowbase + llr; if (vr > NN - 1) vr = NN - 1;
  f32x4 acc[8] = {};
#pragma unroll
  for (int t = 0; t < 4; ++t){
    bf16x8 af = *(const bf16x8*)(xb + (size_t)vr * 128 + (t * 4 + sub) * 8);
    const short* bb = Bp + (size_t)(t * 8) * 512 + l * 8;
#pragma unroll
    for (int nf = 0; nf < 8; ++nf){
      bf16x8 bq = *(const bf16x8*)(bb + nf * 512);
      acc[nf] = __builtin_amdgcn_mfma_f32_16x16x32_bf16(af, bq, acc[nf], 0, 0, 0);
    }
  }
  const int lr = l >> 4, lc = l & 15;
#pragma unroll
  for (int nf = 0; nf < 8; ++nf){
    int col = nf * 16 + lc;
    float bv = rb[col];
#pragma unroll
    for (int r = 0; r < 4; ++r){
      int row = rowbase + lr * 4 + r;
      if (row < NN) resb[(size_t)row * 128 + col] = f2bf(acc[nf][r] + bv);
    }
  }
}

// -------- FUSED layer: gather->LDS A-tile (K=1152) -> barrier -> GEMM -------
// 1024 threads, BM=32. A-tile [32 rows][RSTRIDE bytes] = 72.5 KB (2 blk/CU).
// Row stride 2320 B -> banks rotate 4/row: no swizzle needed, min conflicts.
// Phase 1: 128 8-lane groups; each handles segments g and g+128 (offs bounds
// + first-edge src prefetched; depth-1 row pipeline), groups 0-31 also copy
// the root row. Phase 2: 16 waves, wave w = (mf=w>>3, nf=w&7): 1 acc,
// 2 ds_read + 2 L2-hot B loads + 2 MFMA per kt, no barriers.
#define ACC1(P0, P1) do{ \
  _Pragma("unroll") \
  for (int i_ = 0; i_ < 4; ++i_){ \
    s[2*i_]     += __uint_as_float((P0)[i_] << 16); \
    s[2*i_+1]   += __uint_as_float((P0)[i_] & 0xffff0000u); \
    s[8+2*i_]   += __uint_as_float((P1)[i_] << 16); \
    s[8+2*i_+1] += __uint_as_float((P1)[i_] & 0xffff0000u); \
  } }while(0)

template<int OUTMODE>
__launch_bounds__(1024, 8)
__global__ void fused_k(const u32* __restrict__ offs, const int* __restrict__ elist,
                        const unsigned short* __restrict__ h,
                        const short* __restrict__ Bp,
                        const float* __restrict__ bias,
                        const unsigned short* __restrict__ resb,
                        float* __restrict__ outf, unsigned short* __restrict__ outb){
  __shared__ char Ab[32 * RSTRIDE];          // 72.5 KB
  const int tid = threadIdx.x;
  const int mbase = blockIdx.x * 32;

  // ---------- phase 1: gather ----------
  {
    const int g = tid >> 3, ll8 = tid & 7;
    const unsigned short* hb = h + (size_t)ll8 * 16;
    // two segment tasks: g and g+128
    int r0 = g >> 5, row0 = g & 31;
    int t1 = g + 128;
    int r1 = t1 >> 5, row1 = t1 & 31;
    int v0 = mbase + row0; if (v0 > NN - 1) v0 = NN - 1;
    int v1 = mbase + row1; if (v1 > NN - 1) v1 = NN - 1;
    size_t sg0 = (size_t)r0 * NN + v0, sg1 = (size_t)r1 * NN + v1;
    u32 b0 = offs[sg0], e0 = offs[sg0 + 1];
    u32 b1 = offs[sg1], e1 = offs[sg1 + 1];
    int fs0 = (b0 < e0) ? elist[b0] : 0;
    int fs1 = (b1 < e1) ? elist[b1] : 0;     // prefetched: task1 chain = row load only

#define GATHER(BEG, END, FS, ROW, RSEG) do{ \
    float s[16]; \
    _Pragma("unroll") for (int i_ = 0; i_ < 16; ++i_) s[i_] = 0.f; \
    u32 deg_ = (END) - (BEG); \
    if (deg_){ \
      const unsigned short* rp_ = hb + (size_t)(FS) * 128; \
      u32x4 c0_ = *(const u32x4*)rp_, c1_ = *(const u32x4*)(rp_ + 8); \
      for (u32 e_ = (BEG) + 1; e_ < (END); ++e_){ \
        int nv_ = elist[e_]; \
        const unsigned short* np_ = hb + (size_t)nv_ * 128; \
        u32x4 n0_ = *(const u32x4*)np_, n1_ = *(const u32x4*)(np_ + 8); \
        ACC1(c0_, c1_); \
        c0_ = n0_; c1_ = n1_; \
      } \
      ACC1(c0_, c1_); \
      float inv_ = __builtin_amdgcn_rcpf((float)deg_); \
      _Pragma("unroll") for (int i_ = 0; i_ < 16; ++i_) s[i_] *= inv_; \
    } \
    u32x4 o0_, o1_; \
    _Pragma("unroll") \
    for (int i_ = 0; i_ < 4; ++i_){ \
      o0_[i_] = (u32)f2bf(s[2*i_])   | ((u32)f2bf(s[2*i_+1])   << 16); \
      o1_[i_] = (u32)f2bf(s[8+2*i_]) | ((u32)f2bf(s[8+2*i_+1]) << 16); \
    } \
    char* wp_ = Ab + (ROW) * RSTRIDE + ((RSEG) * 16 + ll8 * 2) * 16; \
    *(u32x4*)wp_ = o0_; \
    *(u32x4*)(wp_ + 16) = o1_; \
  }while(0)

    GATHER(b0, e0, fs0, row0, r0);
    GATHER(b1, e1, fs1, row1, r1);
#undef GATHER
    if (g < 32){                             // root row copy, slots 128..143
      int row = g;
      int v = mbase + row; if (v > NN - 1) v = NN - 1;
      const unsigned short* rp = h + (size_t)v * 128 + ll8 * 16;
      u32x4 o0 = *(const u32x4*)rp, o1 = *(const u32x4*)(rp + 8);
      char* wp = Ab + row * RSTRIDE + (128 + ll8 * 2) * 16;
      *(u32x4*)wp = o0;
      *(u32x4*)(wp + 16) = o1;
    }
  }
  __syncthreads();

  // ---------- phase 2: GEMM ----------
  const int w = tid >> 6, l = tid & 63;
  const int mf = w >> 3, nf = w & 7;
  const int sub = l >> 4, llr = l & 15;
  const int rowb = mf * 16 + llr;
  f32x4 acc = {};
#pragma unroll 6
  for (int kt = 0; kt < 18; ++kt){
#pragma unroll
    for (int t = 0; t < 2; ++t){
      int ks = kt * 8 + t * 4 + sub;
      bf16x8 af = *(const bf16x8*)(Ab + rowb * RSTRIDE + ks * 16);
      bf16x8 bq = *(const bf16x8*)(Bp + ((size_t)((kt * 2 + t) * 8 + nf)) * 512 + l * 8);
      acc = __builtin_amdgcn_mfma_f32_16x16x32_bf16(af, bq, acc, 0, 0, 0);
    }
  }

  // ---------- epilogue ----------
  const int lr = l >> 4, lc = l & 15;
  int col = nf * 16 + lc;
  float bv = bias[col];
#pragma unroll
  for (int r = 0; r < 4; ++r){
    int row = mbase + mf * 16 + lr * 4 + r;
    if (row < NN){
      float v = acc[r] + bv;
      v = bf2f(resb[(size_t)row * 128 + col]) + fmaxf(v, 0.f);
      if (OUTMODE == 1) outb[(size_t)row * 128 + col] = f2bf(v);
      else              outf[(size_t)row * 128 + col] = v;
    }
  }
}

extern "C" void kernel_launch(void* const* d_in, const int* in_sizes, int n_in,
                              void* d_out, int out_size, void* d_ws, size_t ws_size,
                              hipStream_t stream){
  const float* x  = (const float*)d_in[0];
  const int*   ei = (const int*)d_in[1];
  const int*   et = (const int*)d_in[2];
  const float* W1 = (const float*)d_in[3];
  const float* r1 = (const float*)d_in[4];
  const float* b1 = (const float*)d_in[5];
  const float* W2 = (const float*)d_in[6];
  const float* r2 = (const float*)d_in[7];
  const float* b2 = (const float*)d_in[8];
  const float* W3 = (const float*)d_in[9];
  const float* r3 = (const float*)d_in[10];
  const float* b3 = (const float*)d_in[11];
  const float* rw = (const float*)d_in[12];
  const float* rb = (const float*)d_in[13];
  const int* srcv = ei;
  const int* dstv = ei + EE;

  char* p = (char*)d_ws;
  auto take = [&](size_t b)->char*{ char* q = p; p += (b + 255) & ~(size_t)255; return q; };
  unsigned short* xb   = (unsigned short*)take((size_t)NN * 128 * 2);
  unsigned short* h1   = (unsigned short*)take((size_t)NN * 128 * 2);
  unsigned short* h2   = (unsigned short*)take((size_t)NN * 128 * 2);
  unsigned short* resb = (unsigned short*)take((size_t)NN * 128 * 2);
  short* Bp1 = (short*)take(36 * 4096 * 2);
  short* Bp2 = (short*)take(36 * 4096 * 2);
  short* Bp3 = (short*)take(36 * 4096 * 2);
  short* BpR = (short*)take(4 * 4096 * 2);
  u32* cnt   = (u32*)take((size_t)NSEG * 4);
  u32* offs  = (u32*)take((size_t)(NSEG + 1) * 4);
  int* elist = (int*)take((size_t)EE * 4);
  u32* bsum  = (u32*)take((size_t)NB_SCAN * 4);

  hipMemsetAsync(cnt, 0, (size_t)NSEG * 4, stream);

  // conversions + weight packing (once)
  cvt_k<<<(NN * 128 / 4 + 255) / 256, 256, 0, stream>>>(x, xb, NN * 128 / 4);
  packall_k<<<(112 * 512 + 255) / 256, 256, 0, stream>>>(W1, r1, W2, r2, W3, r3, rw,
                                                         Bp1, Bp2, Bp3, BpR);

  // CSR over segments (etype*NN + dst), once for all layers
  count_k<<<(EE + 255) / 256, 256, 0, stream>>>(dstv, et, cnt);
  scan1_k<<<NB_SCAN, 256, 0, stream>>>(cnt, offs, bsum);
  scan2_k<<<1, 512, 0, stream>>>(bsum);
  scan3_k<<<NB_SCAN, 256, 0, stream>>>(offs, bsum);
  fill_k<<<(EE + 255) / 256, 256, 0, stream>>>(srcv, dstv, et, offs, cnt, elist);

  const int GB = (NN + 31) / 32;  // 1563

  // res = bf16(x @ res_w + res_b)
  resg_k<<<(NN + 63) / 64, 256, 0, stream>>>(xb, BpR, rb, resb);

  // fused layers
  fused_k<1><<<GB, 1024, 0, stream>>>(offs, elist, xb, Bp1, b1, resb, nullptr, h1);
  fused_k<1><<<GB, 1024, 0, stream>>>(offs, elist, h1, Bp2, b2, resb, nullptr, h2);
  fused_k<2><<<GB, 1024, 0, stream>>>(offs, elist, h2, Bp3, b3, resb, (float*)d_out, nullptr);
}

// Round 19
// 305.352 us; speedup vs baseline: 1.3109x; 1.0147x over previous
//
#include <hip/hip_runtime.h>
#include <hip/hip_bf16.h>

#define NN 50000
#define EE 600000
#define RR 8
#define NSEG (NN*RR)                     // 400000
#define NB_SCAN ((NSEG + 1023)/1024)     // 391
#define RSTRIDE 2320                     // A-tile row stride in BYTES

typedef unsigned int u32;
typedef __attribute__((ext_vector_type(8))) short bf16x8;
typedef __attribute__((ext_vector_type(4))) float f32x4;
typedef __attribute__((ext_vector_type(4))) u32 u32x4;

// fp32 -> bf16 round-to-nearest-even (finite inputs only)
__device__ inline unsigned short f2bf(float f){
  u32 u = __float_as_uint(f);
  u32 r = (u + 0x7fffu + ((u >> 16) & 1u)) >> 16;
  return (unsigned short)r;
}
__device__ inline float bf2f(unsigned short b){ return __uint_as_float((u32)b << 16); }

// ---------------- conversion: fp32 -> bf16, 4 elems/thread ----------------
__global__ void cvt_k(const float* __restrict__ in, unsigned short* __restrict__ out, int n4){
  int i = blockIdx.x * 256 + threadIdx.x;
  if (i >= n4) return;
  float4 v = ((const float4*)in)[i];
  ushort4 o;
  o.x = f2bf(v.x); o.y = f2bf(v.y); o.z = f2bf(v.z); o.w = f2bf(v.w);
  ((ushort4*)out)[i] = o;
}

// ---------------- pack ALL B stacks into MFMA fragment order ---------------
__global__ void packall_k(const float* __restrict__ W1, const float* __restrict__ r1,
                          const float* __restrict__ W2, const float* __restrict__ r2,
                          const float* __restrict__ W3, const float* __restrict__ r3,
                          const float* __restrict__ rw,
                          short* __restrict__ Bp1, short* __restrict__ Bp2,
                          short* __restrict__ Bp3, short* __restrict__ BpR){
  int tid = blockIdx.x * 256 + threadIdx.x;
  if (tid >= 112 * 512) return;
  int unit = tid >> 9;
  const float* Wrel; const float* root; short* Bp; int k32; int krel;
  if      (unit < 36){ Wrel = W1; root = r1; Bp = Bp1; k32 = unit;       krel = 1024; }
  else if (unit < 72){ Wrel = W2; root = r2; Bp = Bp2; k32 = unit - 36;  krel = 1024; }
  else if (unit <108){ Wrel = W3; root = r3; Bp = Bp3; k32 = unit - 72;  krel = 1024; }
  else               { Wrel = rw; root = rw; Bp = BpR; k32 = unit - 108; krel = 0;    }
  int lane = tid & 63;
  int nf   = (tid >> 6) & 7;
  int col  = nf * 16 + (lane & 15);
  short vals[8];
#pragma unroll
  for (int i = 0; i < 8; ++i){
    int kk = k32 * 32 + ((lane >> 4) << 3) + i;
    float f = (kk < krel) ? Wrel[(size_t)kk * 128 + col]
                          : root[(size_t)(kk - krel) * 128 + col];
    vals[i] = (short)f2bf(f);
  }
  *(bf16x8*)(Bp + (size_t)(k32 * 512 + (tid & 511)) * 8) = *(const bf16x8*)vals;
}

// ---------------- CSR build (relation-major: seg = r*NN + dst) -------------
__global__ void count_k(const int* __restrict__ dst, const int* __restrict__ et,
                        u32* __restrict__ cnt){
  int e = blockIdx.x * 256 + threadIdx.x;
  if (e >= EE) return;
  atomicAdd(&cnt[(size_t)et[e] * NN + dst[e]], 1u);
}

__global__ void scan1_k(const u32* __restrict__ cnt, u32* __restrict__ offs, u32* __restrict__ bsum){
  __shared__ u32 s[512];
  int t = threadIdx.x;                       // 256 threads
  int base = blockIdx.x * 1024 + t * 4;
  u32 loc[4]; u32 sum = 0;
#pragma unroll
  for (int i = 0; i < 4; ++i){ loc[i] = (base + i < NSEG) ? cnt[base + i] : 0u; sum += loc[i]; }
  int pb = 0;
  s[t] = sum; __syncthreads();
  for (int off = 1; off < 256; off <<= 1){
    u32 v = s[pb * 256 + t];
    if (t >= off) v += s[pb * 256 + t - off];
    s[(pb ^ 1) * 256 + t] = v; pb ^= 1; __syncthreads();
  }
  u32 incl = s[pb * 256 + t];
  u32 excl = incl - sum;
  if (t == 255) bsum[blockIdx.x] = incl;
  u32 run = excl;
#pragma unroll
  for (int i = 0; i < 4; ++i){ if (base + i < NSEG) offs[base + i] = run; run += loc[i]; }
}

__global__ void scan2_k(u32* __restrict__ bsum){
  __shared__ u32 s[1024];
  int t = threadIdx.x;                       // 512 threads
  u32 v = (t < NB_SCAN) ? bsum[t] : 0u;
  int pb = 0;
  s[t] = v; __syncthreads();
  for (int off = 1; off < 512; off <<= 1){
    u32 x = s[pb * 512 + t];
    if (t >= off) x += s[pb * 512 + t - off];
    s[(pb ^ 1) * 512 + t] = x; pb ^= 1; __syncthreads();
  }
  u32 incl = s[pb * 512 + t];
  if (t < NB_SCAN) bsum[t] = incl - v;       // exclusive
}

__global__ void scan3_k(u32* __restrict__ offs, const u32* __restrict__ bsum){
  int t = threadIdx.x;
  int base = blockIdx.x * 1024 + t * 4;
  u32 add = bsum[blockIdx.x];
#pragma unroll
  for (int i = 0; i < 4; ++i){ if (base + i < NSEG) offs[base + i] += add; }
  if (blockIdx.x == 0 && t == 0) offs[NSEG] = EE;
}

// fill: reuse cnt as cursor (atomicSub)
__global__ void fill_k(const int* __restrict__ src, const int* __restrict__ dst,
                       const int* __restrict__ et, const u32* __restrict__ offs,
                       u32* __restrict__ cnt, int* __restrict__ elist){
  int e = blockIdx.x * 256 + threadIdx.x;
  if (e >= EE) return;
  int s = et[e] * NN + dst[e];
  u32 p = atomicSub(&cnt[s], 1u);
  elist[offs[s] + p - 1] = src[e];
}

// ---------------- res projection: resb = bf16(x @ res_w + res_b) ----------
__launch_bounds__(256, 4)
__global__ void resg_k(const unsigned short* __restrict__ xb, const short* __restrict__ Bp,
                       const float* __restrict__ rb, unsigned short* __restrict__ resb){
  const int tid = threadIdx.x;
  const int w = tid >> 6, l = tid & 63;
  const int sub = l >> 4, llr = l & 15;
  const int rowbase = blockIdx.x * 64 + w * 16;
  int vr = rowbase + llr; if (vr > NN - 1) vr = NN - 1;
  f32x4 acc[8] = {};
#pragma unroll
  for (int t = 0; t < 4; ++t){
    bf16x8 af = *(const bf16x8*)(xb + (size_t)vr * 128 + (t * 4 + sub) * 8);
    const short* bb = Bp + (size_t)(t * 8) * 512 + l * 8;
#pragma unroll
    for (int nf = 0; nf < 8; ++nf){
      bf16x8 bq = *(const bf16x8*)(bb + nf * 512);
      acc[nf] = __builtin_amdgcn_mfma_f32_16x16x32_bf16(af, bq, acc[nf], 0, 0, 0);
    }
  }
  const int lr = l >> 4, lc = l & 15;
#pragma unroll
  for (int nf = 0; nf < 8; ++nf){
    int col = nf * 16 + lc;
    float bv = rb[col];
#pragma unroll
    for (int r = 0; r < 4; ++r){
      int row = rowbase + lr * 4 + r;
      if (row < NN) resb[(size_t)row * 128 + col] = f2bf(acc[nf][r] + bv);
    }
  }
}

// ---- per-segment gather with 4-wide edge batching (4 loads in flight) -----
#define ACC1(P0, P1) do{ \
  _Pragma("unroll") \
  for (int i_ = 0; i_ < 4; ++i_){ \
    s[2*i_]     += __uint_as_float((P0)[i_] << 16); \
    s[2*i_+1]   += __uint_as_float((P0)[i_] & 0xffff0000u); \
    s[8+2*i_]   += __uint_as_float((P1)[i_] << 16); \
    s[8+2*i_+1] += __uint_as_float((P1)[i_] & 0xffff0000u); \
  } }while(0)

__device__ __forceinline__ void gather_seg(u32 beg, u32 end,
                                           const unsigned short* __restrict__ hb,
                                           const int* __restrict__ elist,
                                           char* __restrict__ Ab,
                                           int row, int rseg, int ll8){
  float s[16];
#pragma unroll
  for (int i = 0; i < 16; ++i) s[i] = 0.f;
  u32 e = beg;
  for (; e + 4 <= end; e += 4){
    int s0 = elist[e], s1 = elist[e+1], s2 = elist[e+2], s3 = elist[e+3];
    const unsigned short* r0 = hb + (size_t)s0 * 128;
    const unsigned short* r1 = hb + (size_t)s1 * 128;
    const unsigned short* r2 = hb + (size_t)s2 * 128;
    const unsigned short* r3 = hb + (size_t)s3 * 128;
    u32x4 p00 = *(const u32x4*)r0, p01 = *(const u32x4*)(r0 + 8);
    u32x4 p10 = *(const u32x4*)r1, p11 = *(const u32x4*)(r1 + 8);
    u32x4 p20 = *(const u32x4*)r2, p21 = *(const u32x4*)(r2 + 8);
    u32x4 p30 = *(const u32x4*)r3, p31 = *(const u32x4*)(r3 + 8);
    ACC1(p00, p01); ACC1(p10, p11); ACC1(p20, p21); ACC1(p30, p31);
  }
  if (e + 2 <= end){
    int s0 = elist[e], s1 = elist[e+1];
    const unsigned short* r0 = hb + (size_t)s0 * 128;
    const unsigned short* r1 = hb + (size_t)s1 * 128;
    u32x4 p00 = *(const u32x4*)r0, p01 = *(const u32x4*)(r0 + 8);
    u32x4 p10 = *(const u32x4*)r1, p11 = *(const u32x4*)(r1 + 8);
    ACC1(p00, p01); ACC1(p10, p11);
    e += 2;
  }
  if (e < end){
    int s0 = elist[e];
    const unsigned short* r0 = hb + (size_t)s0 * 128;
    u32x4 p00 = *(const u32x4*)r0, p01 = *(const u32x4*)(r0 + 8);
    ACC1(p00, p01);
  }
  u32 deg = end - beg;
  if (deg){
    float inv = __builtin_amdgcn_rcpf((float)deg);
#pragma unroll
    for (int i = 0; i < 16; ++i) s[i] *= inv;
  }
  u32x4 o0, o1;
#pragma unroll
  for (int i = 0; i < 4; ++i){
    o0[i] = (u32)f2bf(s[2*i])   | ((u32)f2bf(s[2*i+1])   << 16);
    o1[i] = (u32)f2bf(s[8+2*i]) | ((u32)f2bf(s[8+2*i+1]) << 16);
  }
  char* wp = Ab + row * RSTRIDE + (rseg * 16 + ll8 * 2) * 16;
  *(u32x4*)wp = o0;
  *(u32x4*)(wp + 16) = o1;
}

// -------- FUSED layer: gather->LDS A-tile (K=1152) -> barrier -> GEMM -------
// 1024 threads, BM=32. A-tile [32 rows][RSTRIDE] = 72.5 KB (2 blk/CU).
// Phase 1: 128 8-lane groups x 2 segments each, 4-wide edge batching
// (4 row loads in flight/group; the two task calls are independent so the
// scheduler overlaps task1's head under task0's tail). Groups 0-31 copy root.
// Phase 2: 16 waves, wave w=(mf,nf): 1 acc, no barriers, B L2-hot.
template<int OUTMODE>
__launch_bounds__(1024, 8)
__global__ void fused_k(const u32* __restrict__ offs, const int* __restrict__ elist,
                        const unsigned short* __restrict__ h,
                        const short* __restrict__ Bp,
                        const float* __restrict__ bias,
                        const unsigned short* __restrict__ resb,
                        float* __restrict__ outf, unsigned short* __restrict__ outb){
  __shared__ char Ab[32 * RSTRIDE];          // 72.5 KB
  const int tid = threadIdx.x;
  const int mbase = blockIdx.x * 32;

  // ---------- phase 1: gather ----------
  {
    const int g = tid >> 3, ll8 = tid & 7;
    const unsigned short* hb = h + (size_t)ll8 * 16;
    int r0 = g >> 5, row0 = g & 31;
    int t1 = g + 128;
    int r1 = t1 >> 5, row1 = t1 & 31;
    int v0 = mbase + row0; if (v0 > NN - 1) v0 = NN - 1;
    int v1 = mbase + row1; if (v1 > NN - 1) v1 = NN - 1;
    size_t sg0 = (size_t)r0 * NN + v0, sg1 = (size_t)r1 * NN + v1;
    u32 b0 = offs[sg0], e0 = offs[sg0 + 1];
    u32 b1 = offs[sg1], e1 = offs[sg1 + 1];
    gather_seg(b0, e0, hb, elist, Ab, row0, r0, ll8);
    gather_seg(b1, e1, hb, elist, Ab, row1, r1, ll8);
    if (g < 32){                             // root row copy, slots 128..143
      int row = g;
      int v = mbase + row; if (v > NN - 1) v = NN - 1;
      const unsigned short* rp = h + (size_t)v * 128 + ll8 * 16;
      u32x4 o0 = *(const u32x4*)rp, o1 = *(const u32x4*)(rp + 8);
      char* wp = Ab + row * RSTRIDE + (128 + ll8 * 2) * 16;
      *(u32x4*)wp = o0;
      *(u32x4*)(wp + 16) = o1;
    }
  }
  __syncthreads();

  // ---------- phase 2: GEMM ----------
  const int w = tid >> 6, l = tid & 63;
  const int mf = w >> 3, nf = w & 7;
  const int sub = l >> 4, llr = l & 15;
  const int rowb = mf * 16 + llr;
  f32x4 acc = {};
#pragma unroll 6
  for (int kt = 0; kt < 18; ++kt){
#pragma unroll
    for (int t = 0; t < 2; ++t){
      int ks = kt * 8 + t * 4 + sub;
      bf16x8 af = *(const bf16x8*)(Ab + rowb * RSTRIDE + ks * 16);
      bf16x8 bq = *(const bf16x8*)(Bp + ((size_t)((kt * 2 + t) * 8 + nf)) * 512 + l * 8);
      acc = __builtin_amdgcn_mfma_f32_16x16x32_bf16(af, bq, acc, 0, 0, 0);
    }
  }

  // ---------- epilogue ----------
  const int lr = l >> 4, lc = l & 15;
  int col = nf * 16 + lc;
  float bv = bias[col];
#pragma unroll
  for (int r = 0; r < 4; ++r){
    int row = mbase + mf * 16 + lr * 4 + r;
    if (row < NN){
      float v = acc[r] + bv;
      v = bf2f(resb[(size_t)row * 128 + col]) + fmaxf(v, 0.f);
      if (OUTMODE == 1) outb[(size_t)row * 128 + col] = f2bf(v);
      else              outf[(size_t)row * 128 + col] = v;
    }
  }
}

extern "C" void kernel_launch(void* const* d_in, const int* in_sizes, int n_in,
                              void* d_out, int out_size, void* d_ws, size_t ws_size,
                              hipStream_t stream){
  const float* x  = (const float*)d_in[0];
  const int*   ei = (const int*)d_in[1];
  const int*   et = (const int*)d_in[2];
  const float* W1 = (const float*)d_in[3];
  const float* r1 = (const float*)d_in[4];
  const float* b1 = (const float*)d_in[5];
  const float* W2 = (const float*)d_in[6];
  const float* r2 = (const float*)d_in[7];
  const float* b2 = (const float*)d_in[8];
  const float* W3 = (const float*)d_in[9];
  const float* r3 = (const float*)d_in[10];
  const float* b3 = (const float*)d_in[11];
  const float* rw = (const float*)d_in[12];
  const float* rb = (const float*)d_in[13];
  const int* srcv = ei;
  const int* dstv = ei + EE;

  char* p = (char*)d_ws;
  auto take = [&](size_t b)->char*{ char* q = p; p += (b + 255) & ~(size_t)255; return q; };
  unsigned short* xb   = (unsigned short*)take((size_t)NN * 128 * 2);
  unsigned short* h1   = (unsigned short*)take((size_t)NN * 128 * 2);
  unsigned short* h2   = (unsigned short*)take((size_t)NN * 128 * 2);
  unsigned short* resb = (unsigned short*)take((size_t)NN * 128 * 2);
  short* Bp1 = (short*)take(36 * 4096 * 2);
  short* Bp2 = (short*)take(36 * 4096 * 2);
  short* Bp3 = (short*)take(36 * 4096 * 2);
  short* BpR = (short*)take(4 * 4096 * 2);
  u32* cnt   = (u32*)take((size_t)NSEG * 4);
  u32* offs  = (u32*)take((size_t)(NSEG + 1) * 4);
  int* elist = (int*)take((size_t)EE * 4);
  u32* bsum  = (u32*)take((size_t)NB_SCAN * 4);

  hipMemsetAsync(cnt, 0, (size_t)NSEG * 4, stream);

  // conversions + weight packing (once)
  cvt_k<<<(NN * 128 / 4 + 255) / 256, 256, 0, stream>>>(x, xb, NN * 128 / 4);
  packall_k<<<(112 * 512 + 255) / 256, 256, 0, stream>>>(W1, r1, W2, r2, W3, r3, rw,
                                                         Bp1, Bp2, Bp3, BpR);

  // CSR over segments (etype*NN + dst), once for all layers
  count_k<<<(EE + 255) / 256, 256, 0, stream>>>(dstv, et, cnt);
  scan1_k<<<NB_SCAN, 256, 0, stream>>>(cnt, offs, bsum);
  scan2_k<<<1, 512, 0, stream>>>(bsum);
  scan3_k<<<NB_SCAN, 256, 0, stream>>>(offs, bsum);
  fill_k<<<(EE + 255) / 256, 256, 0, stream>>>(srcv, dstv, et, offs, cnt, elist);

  const int GB = (NN + 31) / 32;  // 1563

  // res = bf16(x @ res_w + res_b)
  resg_k<<<(NN + 63) / 64, 256, 0, stream>>>(xb, BpR, rb, resb);

  // fused layers
  fused_k<1><<<GB, 1024, 0, stream>>>(offs, elist, xb, Bp1, b1, resb, nullptr, h1);
  fused_k<1><<<GB, 1024, 0, stream>>>(offs, elist, h1, Bp2, b2, resb, nullptr, h2);
  fused_k<2><<<GB, 1024, 0, stream>>>(offs, elist, h2, Bp3, b3, resb, (float*)d_out, nullptr);
}